// Round 2
// baseline (431.943 us; speedup 1.0000x reference)
//
#include <hip/hip_runtime.h>
#include <hip/hip_bf16.h>

#define N_NODES 100000
#define N_EDGES 1600000
#define FEAT 128
#define N_GRAPHS 1024
#define NBUCK 391   // ceil(N_NODES/256) windows of 256 nodes (bucket = dst >> 8)
#define CHUNK 4096  // edges per k_bucket block
#define NTILES 1563 // ceil(N_NODES/64) gemm row tiles
#define G1A 781     // gemm1 tiles overlapped with bucket
#define G1B 782     // gemm1 tiles overlapped with bfill

typedef short short8 __attribute__((ext_vector_type(8)));
typedef float float4v __attribute__((ext_vector_type(4)));

static __device__ inline unsigned short f2bf(float f) {
    __hip_bfloat16 b = __float2bfloat16(f);
    unsigned short r;
    __builtin_memcpy(&r, &b, 2);
    return r;
}
static __device__ inline float bf_lo(unsigned int v) { return __uint_as_float(v << 16); }
static __device__ inline float bf_hi(unsigned int v) { return __uint_as_float(v & 0xFFFF0000u); }
static __device__ inline float bf_s(unsigned short s) { return __uint_as_float(((unsigned)s) << 16); }

// ---------------- dispatch 1: W-split prep (blocks 0..127) + dst histogram (blocks 128..383) ----------
__global__ __launch_bounds__(256) void k_prep_hist(const float* __restrict__ W1,
                                                   const float* __restrict__ W2,
                                                   unsigned short* __restrict__ wp1,
                                                   unsigned short* __restrict__ wp2,
                                                   const int* __restrict__ dst,
                                                   int* __restrict__ bcount,
                                                   unsigned int* __restrict__ udummy,
                                                   float* __restrict__ dinv) {
    int bid = blockIdx.x;
    if (bid < 128) {
        const float* W = (bid < 64) ? W1 : W2;
        unsigned short* wp = (bid < 64) ? wp1 : wp2;
        int t = (bid & 63) * 256 + threadIdx.x;  // 0..16383
        int k = t >> 7, n = t & 127;
        float w = W[k * 128 + n];
        unsigned ub = __float_as_uint(w);
        unsigned short hi = (unsigned short)(ub >> 16);  // truncation split
        float hif = __uint_as_float(ub & 0xFFFF0000u);
        unsigned short lo = f2bf(w - hif);               // RNE residual
        int sidx = n * 128 + ((k & 7) | (8 * (((k >> 3) ^ n) & 15)));
        wp[sidx] = hi;
        wp[16384 + sidx] = lo;
        if (bid == 0) {
            if (threadIdx.x < 64) udummy[threadIdx.x] = 0;
            if (threadIdx.x == 64) dinv[N_NODES] = 0.f;
        }
    } else {
        __shared__ int h[NBUCK];
        for (int i = threadIdx.x; i < NBUCK; i += 256) h[i] = 0;
        __syncthreads();
        int hb = bid - 128;
        for (int e = hb * 256 + threadIdx.x; e < N_EDGES; e += 256 * 256)
            atomicAdd(&h[dst[e] >> 8], 1);
        __syncthreads();
        for (int i = threadIdx.x; i < NBUCK; i += 256) {
            int c = h[i];
            if (c) atomicAdd(&bcount[i], c);
        }
    }
}

// ---------------- dispatch 2: exclusive scan of 391 bucket counts (single block) ----------------
// bbase doubles as the CSR window base (wbase==bbase: per-bucket deg sum == bucket edge count).
__global__ __launch_bounds__(512) void k_scan391(const int* __restrict__ in,
                                                 int* __restrict__ base,
                                                 int* __restrict__ cur,
                                                 int* __restrict__ tail) {
    int t = threadIdx.x;
    int v = (t < NBUCK) ? in[t] : 0;
    int lane = t & 63, wid = t >> 6;
    int s = v;
#pragma unroll
    for (int d = 1; d < 64; d <<= 1) { int n = __shfl_up(s, d); if (lane >= d) s += n; }
    __shared__ int ws[8];
    if (lane == 63) ws[wid] = s;
    __syncthreads();
    if (t < 8) {
        int x = ws[t];
#pragma unroll
        for (int d = 1; d < 8; d <<= 1) { int n = __shfl_up(x, d); if ((int)t >= d) x += n; }
        ws[t] = x;
    }
    __syncthreads();
    int excl = s - v + (wid ? ws[wid - 1] : 0);
    if (t < NBUCK) {
        base[t] = excl;
        cur[t] = excl;
    }
    if (t == 0) tail[0] = N_EDGES;
}

// ---------------- shared gemm body: u = bf16(inp @ W) (UNSCALED — dinv applied in agg) ----------------
__device__ __forceinline__ void gemm_f32_body(int tile, const float* __restrict__ inp,
                                              const unsigned short* __restrict__ wp,
                                              unsigned short* __restrict__ u) {
    __shared__ unsigned short sW[32768];  // 64 KB: hi | lo (swizzled)
    {
        float4* d4 = (float4*)sW;
        const float4* s4 = (const float4*)wp;
#pragma unroll
        for (int i = 0; i < 16; ++i) d4[threadIdx.x + 256 * i] = s4[threadIdx.x + 256 * i];
    }
    __syncthreads();
    const int t = threadIdx.x;
    const int wv = t >> 6, L = t & 63;
    const int m = L & 15, q = L >> 4;
    const int r0 = tile * 64 + wv * 16;
    int arow = r0 + m;
    if (arow >= N_NODES) arow = N_NODES - 1;
    const float4* ap = (const float4*)(inp + (size_t)arow * 128);
    float4v acc[8];
#pragma unroll
    for (int c = 0; c < 8; ++c) acc[c] = (float4v){0.f, 0.f, 0.f, 0.f};
#pragma unroll
    for (int k0 = 0; k0 < 128; k0 += 32) {
        float4 f0 = ap[(k0 >> 2) + 2 * q];
        float4 f1 = ap[(k0 >> 2) + 2 * q + 1];
        float fa[8] = {f0.x, f0.y, f0.z, f0.w, f1.x, f1.y, f1.z, f1.w};
        short8 ah, al;
#pragma unroll
        for (int j = 0; j < 8; ++j) {
            unsigned ub = __float_as_uint(fa[j]);
            ah[j] = (short)(ub >> 16);
            float hif = __uint_as_float(ub & 0xFFFF0000u);
            al[j] = (short)f2bf(fa[j] - hif);
        }
        const int b = (k0 >> 3) + q;
#pragma unroll
        for (int c = 0; c < 8; ++c) {
            int ng = c * 16 + m;
            int elem = ng * 128 + 8 * ((b ^ ng) & 15);
            short8 bh = *(const short8*)&sW[elem];
            short8 bl = *(const short8*)&sW[16384 + elem];
            acc[c] = __builtin_amdgcn_mfma_f32_16x16x32_bf16(ah, bh, acc[c], 0, 0, 0);
            acc[c] = __builtin_amdgcn_mfma_f32_16x16x32_bf16(al, bh, acc[c], 0, 0, 0);
            acc[c] = __builtin_amdgcn_mfma_f32_16x16x32_bf16(ah, bl, acc[c], 0, 0, 0);
        }
    }
#pragma unroll
    for (int r = 0; r < 4; ++r) {
        int row = r0 + 4 * q + r;
        if (row < N_NODES) {
            unsigned short* up = u + (size_t)row * 128 + m;
#pragma unroll
            for (int c = 0; c < 8; ++c) up[c * 16] = f2bf(acc[c][r]);
        }
    }
}

// ---------------- dispatch 3: bucket binning (blocks 0..390) + gemm1 tiles 0..780 ----------------
__global__ __launch_bounds__(256) void k_bucket_g1(const int* __restrict__ src,
                                                   const int* __restrict__ dst,
                                                   int* __restrict__ bcur,
                                                   unsigned int* __restrict__ pairs,
                                                   const float* __restrict__ x,
                                                   const unsigned short* __restrict__ wp1,
                                                   unsigned short* __restrict__ u) {
    if (blockIdx.x >= NBUCK) {
        gemm_f32_body(blockIdx.x - NBUCK, x, wp1, u);
        return;
    }
    __shared__ int cnt[NBUCK];
    __shared__ int basebuf[NBUCK];
    int t = threadIdx.x;
    int e0 = blockIdx.x * CHUNK;
    for (int i = t; i < NBUCK; i += 256) cnt[i] = 0;
    __syncthreads();
    unsigned pk[16]; int bk[16];
#pragma unroll
    for (int j = 0; j < 16; ++j) {
        int e = e0 + j * 256 + t;
        if (e < N_EDGES) {
            int s = src[e], d = dst[e];
            bk[j] = d >> 8;
            pk[j] = ((unsigned)s << 8) | (unsigned)(d & 255);
            atomicAdd(&cnt[bk[j]], 1);
        } else bk[j] = -1;
    }
    __syncthreads();
    for (int i = t; i < NBUCK; i += 256) {
        int c = cnt[i];
        basebuf[i] = c ? atomicAdd(&bcur[i], c) : 0;
        cnt[i] = 0;
    }
    __syncthreads();
#pragma unroll
    for (int j = 0; j < 16; ++j) {
        if (bk[j] >= 0) {
            int p = basebuf[bk[j]] + atomicAdd(&cnt[bk[j]], 1);
            pairs[p] = pk[j];
        }
    }
}

// ---------------- dispatch 4: fused deg+dinv+offs+csr fill (blocks 0..390) + gemm1 tiles 781..1562 ----
__global__ __launch_bounds__(256) void k_bfill_g1(const unsigned int* __restrict__ pairs,
                                                  const int* __restrict__ bbase,
                                                  const int* __restrict__ bcount,
                                                  float* __restrict__ dinv,
                                                  int* __restrict__ offs,
                                                  int* __restrict__ csr,
                                                  const float* __restrict__ x,
                                                  const unsigned short* __restrict__ wp1,
                                                  unsigned short* __restrict__ u) {
    if (blockIdx.x >= NBUCK) {
        gemm_f32_body(blockIdx.x - NBUCK + G1A, x, wp1, u);
        return;
    }
    __shared__ int degl[256];
    __shared__ int lcur[256];
    __shared__ int ws[4];
    int b = blockIdx.x, t = threadIdx.x;
    degl[t] = 0;
    __syncthreads();
    int s0 = bbase[b], n = bcount[b];
    for (int i = t; i < n; i += 256) atomicAdd(&degl[pairs[s0 + i] & 255u], 1);
    __syncthreads();
    int node = b * 256 + t;
    int dv = degl[t];
    if (node < N_NODES) dinv[node] = rsqrtf((float)(dv + 1));  // +1 self-loop
    int lane = t & 63, wid = t >> 6;
    int s = dv;
#pragma unroll
    for (int d = 1; d < 64; d <<= 1) { int nn = __shfl_up(s, d); if (lane >= d) s += nn; }
    if (lane == 63) ws[wid] = s;
    __syncthreads();
    if (t < 4) {
        int xx = ws[t];
#pragma unroll
        for (int d = 1; d < 4; d <<= 1) { int nn = __shfl_up(xx, d); if ((int)t >= d) xx += nn; }
        ws[t] = xx;
    }
    __syncthreads();
    int excl = s - dv + (wid ? ws[wid - 1] : 0) + bbase[b];  // wbase == bbase
    if (node < N_NODES) offs[node] = excl;
    lcur[t] = excl;
    __syncthreads();
    for (int i = t; i < n; i += 256) {
        unsigned pr = pairs[s0 + i];
        int p = atomicAdd(&lcur[pr & 255u], 1);
        csr[p] = (int)(pr >> 8);
    }
}

// ---------------- gemm2: bf16 hi/lo plane input, unscaled u out ----------------
__global__ __launch_bounds__(256) void k_gemm_mfma_bf(const unsigned short* __restrict__ hh,
                                                      const unsigned short* __restrict__ hl,
                                                      const unsigned short* __restrict__ wp,
                                                      unsigned short* __restrict__ u) {
    __shared__ unsigned short sW[32768];
    {
        float4* d4 = (float4*)sW;
        const float4* s4 = (const float4*)wp;
#pragma unroll
        for (int i = 0; i < 16; ++i) d4[threadIdx.x + 256 * i] = s4[threadIdx.x + 256 * i];
    }
    __syncthreads();
    const int t = threadIdx.x;
    const int wv = t >> 6, L = t & 63;
    const int m = L & 15, q = L >> 4;
    const int r0 = blockIdx.x * 64 + wv * 16;
    int arow = r0 + m;
    if (arow >= N_NODES) arow = N_NODES - 1;
    const unsigned short* hhp = hh + (size_t)arow * 128 + 8 * q;
    const unsigned short* hlp = hl + (size_t)arow * 128 + 8 * q;
    float4v acc[8];
#pragma unroll
    for (int c = 0; c < 8; ++c) acc[c] = (float4v){0.f, 0.f, 0.f, 0.f};
#pragma unroll
    for (int k0 = 0; k0 < 128; k0 += 32) {
        short8 ah = *(const short8*)(hhp + k0);
        short8 al = *(const short8*)(hlp + k0);
        const int b = (k0 >> 3) + q;
#pragma unroll
        for (int c = 0; c < 8; ++c) {
            int ng = c * 16 + m;
            int elem = ng * 128 + 8 * ((b ^ ng) & 15);
            short8 bh = *(const short8*)&sW[elem];
            short8 bl = *(const short8*)&sW[16384 + elem];
            acc[c] = __builtin_amdgcn_mfma_f32_16x16x32_bf16(ah, bh, acc[c], 0, 0, 0);
            acc[c] = __builtin_amdgcn_mfma_f32_16x16x32_bf16(al, bh, acc[c], 0, 0, 0);
            acc[c] = __builtin_amdgcn_mfma_f32_16x16x32_bf16(ah, bl, acc[c], 0, 0, 0);
        }
    }
#pragma unroll
    for (int r = 0; r < 4; ++r) {
        int row = r0 + 4 * q + r;
        if (row < N_NODES) {
            unsigned short* up = u + (size_t)row * 128 + m;
#pragma unroll
            for (int c = 0; c < 8; ++c) up[c * 16] = f2bf(acc[c][r]);
        }
    }
}

// ---------------- aggregate: h = relu(dinv_i*(sum dinv_s*u[s] + dinv_i*u[i]) + b) ----------------
// u is UNSCALED; dinv applied per edge via scalar loads (FMA replaces ADD, same VALU count).
// hlp != nullptr: emit hi/lo bf16 planes (feeds gemm2).
// hlp == nullptr: layer-2 mode — project h row onto Wl (128x2) in-register and atomicAdd the
//                 2-float per-node partial into outp[graph] (pool fused; k_fin divides by count).
__global__ __launch_bounds__(256) void k_agg(const unsigned int* __restrict__ u,
                                             const int* __restrict__ offs,
                                             const int* __restrict__ csr,
                                             const float* __restrict__ dinv,
                                             const float* __restrict__ bias,
                                             unsigned int* __restrict__ hhp,
                                             unsigned int* __restrict__ hlp,
                                             const float* __restrict__ Wl,
                                             float* __restrict__ outp,
                                             const int* __restrict__ batch) {
    int wid = threadIdx.x >> 6;
    int lane = threadIdx.x & 63;
    int node = __builtin_amdgcn_readfirstlane(blockIdx.x * 4 + wid);
    if (node >= N_NODES) return;
    int p = __builtin_amdgcn_readfirstlane(offs[node]);
    int e = __builtin_amdgcn_readfirstlane(offs[node + 1]);
    float dsf = dinv[node];
    unsigned int self = u[(size_t)node * 64 + lane];
    float ax0 = dsf * bf_lo(self), ay0 = dsf * bf_hi(self);
    float ax1 = 0.f, ay1 = 0.f, ax2 = 0.f, ay2 = 0.f, ax3 = 0.f, ay3 = 0.f;
    float ax4 = 0.f, ay4 = 0.f, ax5 = 0.f, ay5 = 0.f, ax6 = 0.f, ay6 = 0.f;
    float ax7 = 0.f, ay7 = 0.f;
    for (; p < e; p += 8) {
        int c0 = csr[p + 0], c1 = csr[p + 1], c2 = csr[p + 2], c3 = csr[p + 3];
        int c4 = csr[p + 4], c5 = csr[p + 5], c6 = csr[p + 6], c7 = csr[p + 7];
        int i0 = c0;
        int i1 = (p + 1 < e) ? c1 : N_NODES;
        int i2 = (p + 2 < e) ? c2 : N_NODES;
        int i3 = (p + 3 < e) ? c3 : N_NODES;
        int i4 = (p + 4 < e) ? c4 : N_NODES;
        int i5 = (p + 5 < e) ? c5 : N_NODES;
        int i6 = (p + 6 < e) ? c6 : N_NODES;
        int i7 = (p + 7 < e) ? c7 : N_NODES;
        float d0 = dinv[i0], d1 = dinv[i1], d2 = dinv[i2], d3 = dinv[i3];
        float d4 = dinv[i4], d5 = dinv[i5], d6 = dinv[i6], d7 = dinv[i7];
        unsigned v0 = (u + (size_t)i0 * 64)[lane];
        unsigned v1 = (u + (size_t)i1 * 64)[lane];
        unsigned v2 = (u + (size_t)i2 * 64)[lane];
        unsigned v3 = (u + (size_t)i3 * 64)[lane];
        unsigned v4 = (u + (size_t)i4 * 64)[lane];
        unsigned v5 = (u + (size_t)i5 * 64)[lane];
        unsigned v6 = (u + (size_t)i6 * 64)[lane];
        unsigned v7 = (u + (size_t)i7 * 64)[lane];
        ax0 = fmaf(d0, bf_lo(v0), ax0); ay0 = fmaf(d0, bf_hi(v0), ay0);
        ax1 = fmaf(d1, bf_lo(v1), ax1); ay1 = fmaf(d1, bf_hi(v1), ay1);
        ax2 = fmaf(d2, bf_lo(v2), ax2); ay2 = fmaf(d2, bf_hi(v2), ay2);
        ax3 = fmaf(d3, bf_lo(v3), ax3); ay3 = fmaf(d3, bf_hi(v3), ay3);
        ax4 = fmaf(d4, bf_lo(v4), ax4); ay4 = fmaf(d4, bf_hi(v4), ay4);
        ax5 = fmaf(d5, bf_lo(v5), ax5); ay5 = fmaf(d5, bf_hi(v5), ay5);
        ax6 = fmaf(d6, bf_lo(v6), ax6); ay6 = fmaf(d6, bf_hi(v6), ay6);
        ax7 = fmaf(d7, bf_lo(v7), ax7); ay7 = fmaf(d7, bf_hi(v7), ay7);
    }
    float2 b = ((const float2*)bias)[lane];
    float sx = ((ax0 + ax1) + (ax2 + ax3)) + ((ax4 + ax5) + (ax6 + ax7));
    float sy = ((ay0 + ay1) + (ay2 + ay3)) + ((ay4 + ay5) + (ay6 + ay7));
    float r0 = fmaxf(dsf * sx + b.x, 0.f);
    float r1 = fmaxf(dsf * sy + b.y, 0.f);
    if (hlp) {
        unsigned u0 = __float_as_uint(r0), u1 = __float_as_uint(r1);
        unsigned short h0 = (unsigned short)(u0 >> 16), h1 = (unsigned short)(u1 >> 16);
        float rf0 = __uint_as_float(u0 & 0xFFFF0000u), rf1 = __uint_as_float(u1 & 0xFFFF0000u);
        unsigned short l0 = f2bf(r0 - rf0), l1 = f2bf(r1 - rf1);
        hhp[(size_t)node * 64 + lane] = (unsigned)h0 | ((unsigned)h1 << 16);
        hlp[(size_t)node * 64 + lane] = (unsigned)l0 | ((unsigned)l1 << 16);
    } else {
        // fused pool: per-node projection onto Wl, wave-reduce, one atomic pair per node.
        // lane holds channels (2*lane, 2*lane+1); Wl is row-major [128][2].
        float2 wl0 = ((const float2*)Wl)[2 * lane];
        float2 wl1 = ((const float2*)Wl)[2 * lane + 1];
        float p0 = r0 * wl0.x + r1 * wl1.x;
        float p1 = r0 * wl0.y + r1 * wl1.y;
#pragma unroll
        for (int d = 32; d > 0; d >>= 1) {
            p0 += __shfl_xor(p0, d);
            p1 += __shfl_xor(p1, d);
        }
        if (lane == 0) {
            int g = batch[node];
            atomicAdd(&outp[2 * g + 0], p0);
            atomicAdd(&outp[2 * g + 1], p1);
        }
    }
}

// ---------------- finalize: out[g] = out[g]/max(cnt,1) + bl (counts via binary search) ----------
__global__ __launch_bounds__(256) void k_fin(const int* __restrict__ batch,
                                             const float* __restrict__ bl,
                                             float* __restrict__ out) {
    int g = blockIdx.x * 256 + threadIdx.x;
    if (g >= N_GRAPHS) return;
    int lo = 0, hi = N_NODES;
    while (lo < hi) { int m = (lo + hi) >> 1; if (batch[m] < g) lo = m + 1; else hi = m; }
    int s0 = lo;
    hi = N_NODES;
    while (lo < hi) { int m = (lo + hi) >> 1; if (batch[m] < g + 1) lo = m + 1; else hi = m; }
    float inv = 1.f / fmaxf((float)(lo - s0), 1.f);
    out[2 * g + 0] = out[2 * g + 0] * inv + bl[0];
    out[2 * g + 1] = out[2 * g + 1] * inv + bl[1];
}

extern "C" void kernel_launch(void* const* d_in, const int* in_sizes, int n_in,
                              void* d_out, int out_size, void* d_ws, size_t ws_size,
                              hipStream_t stream) {
    const float* x  = (const float*)d_in[0];
    const int* ei   = (const int*)d_in[1];
    const int* batch = (const int*)d_in[2];
    const float* W1 = (const float*)d_in[3];
    const float* b1 = (const float*)d_in[4];
    const float* W2 = (const float*)d_in[5];
    const float* b2 = (const float*)d_in[6];
    const float* Wl = (const float*)d_in[7];
    const float* bl = (const float*)d_in[8];
    float* out = (float*)d_out;
    const int* src = ei;
    const int* dst = ei + N_EDGES;

    char* ws = (char*)d_ws;
    size_t o = 0;
    auto alloc = [&](size_t bytes) -> void* {
        o = (o + 255) & ~(size_t)255;
        void* p = ws + o;
        o += bytes;
        return p;
    };
    int* bcount = (int*)alloc((size_t)NBUCK * 4);
    int* bbase  = (int*)alloc((size_t)NBUCK * 4);
    int* bcur   = (int*)alloc((size_t)NBUCK * 4);
    float* dinv = (float*)alloc((size_t)(N_NODES + 1) * 4);  // +1 zero slot for tail
    int* offs   = (int*)alloc((size_t)(N_NODES + 1) * 4);
    unsigned short* wp1 = (unsigned short*)alloc(65536);
    unsigned short* wp2 = (unsigned short*)alloc(65536);
    unsigned int* pairs = (unsigned int*)alloc((size_t)N_EDGES * 4);
    int* csr    = (int*)alloc((size_t)(N_EDGES + 8) * 4);               // +8 pad for unroll reads
    unsigned short* u = (unsigned short*)alloc((size_t)(N_NODES + 1) * 128 * 2);  // +1 zero row
    unsigned short* hh = (unsigned short*)alloc((size_t)N_NODES * 128 * 2);
    unsigned short* hl = (unsigned short*)alloc((size_t)N_NODES * 128 * 2);

    hipMemsetAsync(bcount, 0, (size_t)NBUCK * 4, stream);
    hipMemsetAsync(out, 0, (size_t)N_GRAPHS * 2 * 4, stream);
    k_prep_hist<<<384, 256, 0, stream>>>(W1, W2, wp1, wp2, dst, bcount,
                                         (unsigned int*)(u + (size_t)N_NODES * 128), dinv);
    k_scan391<<<1, 512, 0, stream>>>(bcount, bbase, bcur, &offs[N_NODES]);
    k_bucket_g1<<<NBUCK + G1A, 256, 0, stream>>>(src, dst, bcur, pairs, x, wp1, u);
    k_bfill_g1<<<NBUCK + G1B, 256, 0, stream>>>(pairs, bbase, bcount, dinv, offs, csr, x, wp1, u);

    k_agg<<<(N_NODES + 3) / 4, 256, 0, stream>>>((const unsigned int*)u, offs, csr, dinv, b1,
                                                 (unsigned int*)hh, (unsigned int*)hl,
                                                 nullptr, nullptr, nullptr);
    k_gemm_mfma_bf<<<NTILES, 256, 0, stream>>>(hh, hl, wp2, u);
    k_agg<<<(N_NODES + 3) / 4, 256, 0, stream>>>((const unsigned int*)u, offs, csr, dinv, b2,
                                                 nullptr, nullptr, Wl, out, batch);

    k_fin<<<(N_GRAPHS + 255) / 256, 256, 0, stream>>>(batch, bl, out);
}

// Round 3
// 321.221 us; speedup vs baseline: 1.3447x; 1.3447x over previous
//
#include <hip/hip_runtime.h>
#include <hip/hip_bf16.h>

#define N_NODES 100000
#define N_EDGES 1600000
#define FEAT 128
#define N_GRAPHS 1024
#define NBUCK 391   // ceil(N_NODES/256) windows of 256 nodes (bucket = dst >> 8)
#define CHUNK 4096  // edges per k_bucket block
#define NTILES 1563 // ceil(N_NODES/64) gemm row tiles
#define G1A 781     // gemm1 tiles overlapped with bucket
#define G1B 782     // gemm1 tiles overlapped with bfill

typedef short short8 __attribute__((ext_vector_type(8)));
typedef float float4v __attribute__((ext_vector_type(4)));

static __device__ inline unsigned short f2bf(float f) {
    __hip_bfloat16 b = __float2bfloat16(f);
    unsigned short r;
    __builtin_memcpy(&r, &b, 2);
    return r;
}
static __device__ inline float bf_lo(unsigned int v) { return __uint_as_float(v << 16); }
static __device__ inline float bf_hi(unsigned int v) { return __uint_as_float(v & 0xFFFF0000u); }

// ---------------- dispatch 1: W-split prep (blocks 0..127) + dst histogram (blocks 128..383) ----------
__global__ __launch_bounds__(256) void k_prep_hist(const float* __restrict__ W1,
                                                   const float* __restrict__ W2,
                                                   unsigned short* __restrict__ wp1,
                                                   unsigned short* __restrict__ wp2,
                                                   const int* __restrict__ dst,
                                                   int* __restrict__ bcount,
                                                   unsigned int* __restrict__ udummy,
                                                   float* __restrict__ dinv) {
    int bid = blockIdx.x;
    if (bid < 128) {
        const float* W = (bid < 64) ? W1 : W2;
        unsigned short* wp = (bid < 64) ? wp1 : wp2;
        int t = (bid & 63) * 256 + threadIdx.x;  // 0..16383
        int k = t >> 7, n = t & 127;
        float w = W[k * 128 + n];
        unsigned ub = __float_as_uint(w);
        unsigned short hi = (unsigned short)(ub >> 16);  // truncation split
        float hif = __uint_as_float(ub & 0xFFFF0000u);
        unsigned short lo = f2bf(w - hif);               // RNE residual
        int sidx = n * 128 + ((k & 7) | (8 * (((k >> 3) ^ n) & 15)));
        wp[sidx] = hi;
        wp[16384 + sidx] = lo;
        if (bid == 0) {
            if (threadIdx.x < 64) udummy[threadIdx.x] = 0;
            if (threadIdx.x == 64) dinv[N_NODES] = 0.f;
        }
    } else {
        __shared__ int h[NBUCK];
        for (int i = threadIdx.x; i < NBUCK; i += 256) h[i] = 0;
        __syncthreads();
        int hb = bid - 128;
        for (int e = hb * 256 + threadIdx.x; e < N_EDGES; e += 256 * 256)
            atomicAdd(&h[dst[e] >> 8], 1);
        __syncthreads();
        for (int i = threadIdx.x; i < NBUCK; i += 256) {
            int c = h[i];
            if (c) atomicAdd(&bcount[i], c);
        }
    }
}

// ---------------- dispatch 2: exclusive scan of 391 bucket counts (single block) ----------------
// bbase doubles as the CSR window base (wbase==bbase: per-bucket deg sum == bucket edge count).
__global__ __launch_bounds__(512) void k_scan391(const int* __restrict__ in,
                                                 int* __restrict__ base,
                                                 int* __restrict__ cur,
                                                 int* __restrict__ tail) {
    int t = threadIdx.x;
    int v = (t < NBUCK) ? in[t] : 0;
    int lane = t & 63, wid = t >> 6;
    int s = v;
#pragma unroll
    for (int d = 1; d < 64; d <<= 1) { int n = __shfl_up(s, d); if (lane >= d) s += n; }
    __shared__ int ws[8];
    if (lane == 63) ws[wid] = s;
    __syncthreads();
    if (t < 8) {
        int x = ws[t];
#pragma unroll
        for (int d = 1; d < 8; d <<= 1) { int n = __shfl_up(x, d); if ((int)t >= d) x += n; }
        ws[t] = x;
    }
    __syncthreads();
    int excl = s - v + (wid ? ws[wid - 1] : 0);
    if (t < NBUCK) {
        base[t] = excl;
        cur[t] = excl;
    }
    if (t == 0) tail[0] = N_EDGES;
}

// ---------------- shared gemm body: u = bf16(inp @ W) (UNSCALED — dinv applied in agg) ----------------
__device__ __forceinline__ void gemm_f32_body(int tile, const float* __restrict__ inp,
                                              const unsigned short* __restrict__ wp,
                                              unsigned short* __restrict__ u) {
    __shared__ unsigned short sW[32768];  // 64 KB: hi | lo (swizzled)
    {
        float4* d4 = (float4*)sW;
        const float4* s4 = (const float4*)wp;
#pragma unroll
        for (int i = 0; i < 16; ++i) d4[threadIdx.x + 256 * i] = s4[threadIdx.x + 256 * i];
    }
    __syncthreads();
    const int t = threadIdx.x;
    const int wv = t >> 6, L = t & 63;
    const int m = L & 15, q = L >> 4;
    const int r0 = tile * 64 + wv * 16;
    int arow = r0 + m;
    if (arow >= N_NODES) arow = N_NODES - 1;
    const float4* ap = (const float4*)(inp + (size_t)arow * 128);
    float4v acc[8];
#pragma unroll
    for (int c = 0; c < 8; ++c) acc[c] = (float4v){0.f, 0.f, 0.f, 0.f};
#pragma unroll
    for (int k0 = 0; k0 < 128; k0 += 32) {
        float4 f0 = ap[(k0 >> 2) + 2 * q];
        float4 f1 = ap[(k0 >> 2) + 2 * q + 1];
        float fa[8] = {f0.x, f0.y, f0.z, f0.w, f1.x, f1.y, f1.z, f1.w};
        short8 ah, al;
#pragma unroll
        for (int j = 0; j < 8; ++j) {
            unsigned ub = __float_as_uint(fa[j]);
            ah[j] = (short)(ub >> 16);
            float hif = __uint_as_float(ub & 0xFFFF0000u);
            al[j] = (short)f2bf(fa[j] - hif);
        }
        const int b = (k0 >> 3) + q;
#pragma unroll
        for (int c = 0; c < 8; ++c) {
            int ng = c * 16 + m;
            int elem = ng * 128 + 8 * ((b ^ ng) & 15);
            short8 bh = *(const short8*)&sW[elem];
            short8 bl = *(const short8*)&sW[16384 + elem];
            acc[c] = __builtin_amdgcn_mfma_f32_16x16x32_bf16(ah, bh, acc[c], 0, 0, 0);
            acc[c] = __builtin_amdgcn_mfma_f32_16x16x32_bf16(al, bh, acc[c], 0, 0, 0);
            acc[c] = __builtin_amdgcn_mfma_f32_16x16x32_bf16(ah, bl, acc[c], 0, 0, 0);
        }
    }
#pragma unroll
    for (int r = 0; r < 4; ++r) {
        int row = r0 + 4 * q + r;
        if (row < N_NODES) {
            unsigned short* up = u + (size_t)row * 128 + m;
#pragma unroll
            for (int c = 0; c < 8; ++c) up[c * 16] = f2bf(acc[c][r]);
        }
    }
}

// ---------------- dispatch 3: bucket binning (blocks 0..390) + gemm1 tiles 0..780 ----------------
__global__ __launch_bounds__(256) void k_bucket_g1(const int* __restrict__ src,
                                                   const int* __restrict__ dst,
                                                   int* __restrict__ bcur,
                                                   unsigned int* __restrict__ pairs,
                                                   const float* __restrict__ x,
                                                   const unsigned short* __restrict__ wp1,
                                                   unsigned short* __restrict__ u) {
    if (blockIdx.x >= NBUCK) {
        gemm_f32_body(blockIdx.x - NBUCK, x, wp1, u);
        return;
    }
    __shared__ int cnt[NBUCK];
    __shared__ int basebuf[NBUCK];
    int t = threadIdx.x;
    int e0 = blockIdx.x * CHUNK;
    for (int i = t; i < NBUCK; i += 256) cnt[i] = 0;
    __syncthreads();
    unsigned pk[16]; int bk[16];
#pragma unroll
    for (int j = 0; j < 16; ++j) {
        int e = e0 + j * 256 + t;
        if (e < N_EDGES) {
            int s = src[e], d = dst[e];
            bk[j] = d >> 8;
            pk[j] = ((unsigned)s << 8) | (unsigned)(d & 255);
            atomicAdd(&cnt[bk[j]], 1);
        } else bk[j] = -1;
    }
    __syncthreads();
    for (int i = t; i < NBUCK; i += 256) {
        int c = cnt[i];
        basebuf[i] = c ? atomicAdd(&bcur[i], c) : 0;
        cnt[i] = 0;
    }
    __syncthreads();
#pragma unroll
    for (int j = 0; j < 16; ++j) {
        if (bk[j] >= 0) {
            int p = basebuf[bk[j]] + atomicAdd(&cnt[bk[j]], 1);
            pairs[p] = pk[j];
        }
    }
}

// ---------------- dispatch 4: fused deg+dinv+offs+csr fill (blocks 0..390) + gemm1 tiles 781..1562 ----
__global__ __launch_bounds__(256) void k_bfill_g1(const unsigned int* __restrict__ pairs,
                                                  const int* __restrict__ bbase,
                                                  const int* __restrict__ bcount,
                                                  float* __restrict__ dinv,
                                                  int* __restrict__ offs,
                                                  int* __restrict__ csr,
                                                  const float* __restrict__ x,
                                                  const unsigned short* __restrict__ wp1,
                                                  unsigned short* __restrict__ u) {
    if (blockIdx.x >= NBUCK) {
        gemm_f32_body(blockIdx.x - NBUCK + G1A, x, wp1, u);
        return;
    }
    __shared__ int degl[256];
    __shared__ int lcur[256];
    __shared__ int ws[4];
    int b = blockIdx.x, t = threadIdx.x;
    degl[t] = 0;
    __syncthreads();
    int s0 = bbase[b], n = bcount[b];
    for (int i = t; i < n; i += 256) atomicAdd(&degl[pairs[s0 + i] & 255u], 1);
    __syncthreads();
    int node = b * 256 + t;
    int dv = degl[t];
    if (node < N_NODES) dinv[node] = rsqrtf((float)(dv + 1));  // +1 self-loop
    int lane = t & 63, wid = t >> 6;
    int s = dv;
#pragma unroll
    for (int d = 1; d < 64; d <<= 1) { int nn = __shfl_up(s, d); if (lane >= d) s += nn; }
    if (lane == 63) ws[wid] = s;
    __syncthreads();
    if (t < 4) {
        int xx = ws[t];
#pragma unroll
        for (int d = 1; d < 4; d <<= 1) { int nn = __shfl_up(xx, d); if ((int)t >= d) xx += nn; }
        ws[t] = xx;
    }
    __syncthreads();
    int excl = s - dv + (wid ? ws[wid - 1] : 0) + bbase[b];  // wbase == bbase
    if (node < N_NODES) offs[node] = excl;
    lcur[t] = excl;
    __syncthreads();
    for (int i = t; i < n; i += 256) {
        unsigned pr = pairs[s0 + i];
        int p = atomicAdd(&lcur[pr & 255u], 1);
        csr[p] = (int)(pr >> 8);
    }
}

// ---------------- gemm2: bf16 hi/lo plane input, unscaled u out ----------------
__global__ __launch_bounds__(256) void k_gemm_mfma_bf(const unsigned short* __restrict__ hh,
                                                      const unsigned short* __restrict__ hl,
                                                      const unsigned short* __restrict__ wp,
                                                      unsigned short* __restrict__ u) {
    __shared__ unsigned short sW[32768];
    {
        float4* d4 = (float4*)sW;
        const float4* s4 = (const float4*)wp;
#pragma unroll
        for (int i = 0; i < 16; ++i) d4[threadIdx.x + 256 * i] = s4[threadIdx.x + 256 * i];
    }
    __syncthreads();
    const int t = threadIdx.x;
    const int wv = t >> 6, L = t & 63;
    const int m = L & 15, q = L >> 4;
    const int r0 = blockIdx.x * 64 + wv * 16;
    int arow = r0 + m;
    if (arow >= N_NODES) arow = N_NODES - 1;
    const unsigned short* hhp = hh + (size_t)arow * 128 + 8 * q;
    const unsigned short* hlp = hl + (size_t)arow * 128 + 8 * q;
    float4v acc[8];
#pragma unroll
    for (int c = 0; c < 8; ++c) acc[c] = (float4v){0.f, 0.f, 0.f, 0.f};
#pragma unroll
    for (int k0 = 0; k0 < 128; k0 += 32) {
        short8 ah = *(const short8*)(hhp + k0);
        short8 al = *(const short8*)(hlp + k0);
        const int b = (k0 >> 3) + q;
#pragma unroll
        for (int c = 0; c < 8; ++c) {
            int ng = c * 16 + m;
            int elem = ng * 128 + 8 * ((b ^ ng) & 15);
            short8 bh = *(const short8*)&sW[elem];
            short8 bl = *(const short8*)&sW[16384 + elem];
            acc[c] = __builtin_amdgcn_mfma_f32_16x16x32_bf16(ah, bh, acc[c], 0, 0, 0);
            acc[c] = __builtin_amdgcn_mfma_f32_16x16x32_bf16(al, bh, acc[c], 0, 0, 0);
            acc[c] = __builtin_amdgcn_mfma_f32_16x16x32_bf16(ah, bl, acc[c], 0, 0, 0);
        }
    }
#pragma unroll
    for (int r = 0; r < 4; ++r) {
        int row = r0 + 4 * q + r;
        if (row < N_NODES) {
            unsigned short* up = u + (size_t)row * 128 + m;
#pragma unroll
            for (int c = 0; c < 8; ++c) up[c * 16] = f2bf(acc[c][r]);
        }
    }
}

// ---------------- aggregate: h = relu(dinv_i*(sum dinv_s*u[s] + dinv_i*u[i]) + b) ----------------
// u is UNSCALED; dinv applied per edge via scalar loads (FMA replaces ADD, same VALU count).
// hlp != nullptr: emit hi/lo bf16 planes (feeds gemm2).
// hlp == nullptr: layer-2 mode — project h row onto Wl (128x2) in-register, wave-reduce, and
//                 write the per-node 2-float partial to pnode[node] (NO atomics — round-2's
//                 same-address atomic serialization cost +113us). k_fin segment-sums pnode.
__global__ __launch_bounds__(256) void k_agg(const unsigned int* __restrict__ u,
                                             const int* __restrict__ offs,
                                             const int* __restrict__ csr,
                                             const float* __restrict__ dinv,
                                             const float* __restrict__ bias,
                                             unsigned int* __restrict__ hhp,
                                             unsigned int* __restrict__ hlp,
                                             const float* __restrict__ Wl,
                                             float* __restrict__ pnode) {
    int wid = threadIdx.x >> 6;
    int lane = threadIdx.x & 63;
    int node = __builtin_amdgcn_readfirstlane(blockIdx.x * 4 + wid);
    if (node >= N_NODES) return;
    int p = __builtin_amdgcn_readfirstlane(offs[node]);
    int e = __builtin_amdgcn_readfirstlane(offs[node + 1]);
    float dsf = dinv[node];
    unsigned int self = u[(size_t)node * 64 + lane];
    float ax0 = dsf * bf_lo(self), ay0 = dsf * bf_hi(self);
    float ax1 = 0.f, ay1 = 0.f, ax2 = 0.f, ay2 = 0.f, ax3 = 0.f, ay3 = 0.f;
    float ax4 = 0.f, ay4 = 0.f, ax5 = 0.f, ay5 = 0.f, ax6 = 0.f, ay6 = 0.f;
    float ax7 = 0.f, ay7 = 0.f;
    for (; p < e; p += 8) {
        int c0 = csr[p + 0], c1 = csr[p + 1], c2 = csr[p + 2], c3 = csr[p + 3];
        int c4 = csr[p + 4], c5 = csr[p + 5], c6 = csr[p + 6], c7 = csr[p + 7];
        int i0 = c0;
        int i1 = (p + 1 < e) ? c1 : N_NODES;
        int i2 = (p + 2 < e) ? c2 : N_NODES;
        int i3 = (p + 3 < e) ? c3 : N_NODES;
        int i4 = (p + 4 < e) ? c4 : N_NODES;
        int i5 = (p + 5 < e) ? c5 : N_NODES;
        int i6 = (p + 6 < e) ? c6 : N_NODES;
        int i7 = (p + 7 < e) ? c7 : N_NODES;
        float d0 = dinv[i0], d1 = dinv[i1], d2 = dinv[i2], d3 = dinv[i3];
        float d4 = dinv[i4], d5 = dinv[i5], d6 = dinv[i6], d7 = dinv[i7];
        unsigned v0 = (u + (size_t)i0 * 64)[lane];
        unsigned v1 = (u + (size_t)i1 * 64)[lane];
        unsigned v2 = (u + (size_t)i2 * 64)[lane];
        unsigned v3 = (u + (size_t)i3 * 64)[lane];
        unsigned v4 = (u + (size_t)i4 * 64)[lane];
        unsigned v5 = (u + (size_t)i5 * 64)[lane];
        unsigned v6 = (u + (size_t)i6 * 64)[lane];
        unsigned v7 = (u + (size_t)i7 * 64)[lane];
        ax0 = fmaf(d0, bf_lo(v0), ax0); ay0 = fmaf(d0, bf_hi(v0), ay0);
        ax1 = fmaf(d1, bf_lo(v1), ax1); ay1 = fmaf(d1, bf_hi(v1), ay1);
        ax2 = fmaf(d2, bf_lo(v2), ax2); ay2 = fmaf(d2, bf_hi(v2), ay2);
        ax3 = fmaf(d3, bf_lo(v3), ax3); ay3 = fmaf(d3, bf_hi(v3), ay3);
        ax4 = fmaf(d4, bf_lo(v4), ax4); ay4 = fmaf(d4, bf_hi(v4), ay4);
        ax5 = fmaf(d5, bf_lo(v5), ax5); ay5 = fmaf(d5, bf_hi(v5), ay5);
        ax6 = fmaf(d6, bf_lo(v6), ax6); ay6 = fmaf(d6, bf_hi(v6), ay6);
        ax7 = fmaf(d7, bf_lo(v7), ax7); ay7 = fmaf(d7, bf_hi(v7), ay7);
    }
    float2 b = ((const float2*)bias)[lane];
    float sx = ((ax0 + ax1) + (ax2 + ax3)) + ((ax4 + ax5) + (ax6 + ax7));
    float sy = ((ay0 + ay1) + (ay2 + ay3)) + ((ay4 + ay5) + (ay6 + ay7));
    float r0 = fmaxf(dsf * sx + b.x, 0.f);
    float r1 = fmaxf(dsf * sy + b.y, 0.f);
    if (hlp) {
        unsigned u0 = __float_as_uint(r0), u1 = __float_as_uint(r1);
        unsigned short h0 = (unsigned short)(u0 >> 16), h1 = (unsigned short)(u1 >> 16);
        float rf0 = __uint_as_float(u0 & 0xFFFF0000u), rf1 = __uint_as_float(u1 & 0xFFFF0000u);
        unsigned short l0 = f2bf(r0 - rf0), l1 = f2bf(r1 - rf1);
        hhp[(size_t)node * 64 + lane] = (unsigned)h0 | ((unsigned)h1 << 16);
        hlp[(size_t)node * 64 + lane] = (unsigned)l0 | ((unsigned)l1 << 16);
    } else {
        // fused pool projection: lane holds channels (2*lane, 2*lane+1); Wl row-major [128][2].
        float2 wl0 = ((const float2*)Wl)[2 * lane];
        float2 wl1 = ((const float2*)Wl)[2 * lane + 1];
        float p0 = r0 * wl0.x + r1 * wl1.x;
        float p1 = r0 * wl0.y + r1 * wl1.y;
#pragma unroll
        for (int d = 32; d > 0; d >>= 1) {
            p0 += __shfl_xor(p0, d);
            p1 += __shfl_xor(p1, d);
        }
        if (lane == 0) {
            float2* pp = (float2*)pnode;
            pp[node] = (float2){p0, p1};
        }
    }
}

// ---------------- finalize: out[g] = segsum(pnode)/max(cnt,1) + bl (1 wave per graph) ----------
__global__ __launch_bounds__(64) void k_fin(const float* __restrict__ pnode,
                                            const int* __restrict__ batch,
                                            const float* __restrict__ bl,
                                            float* __restrict__ out) {
    int g = blockIdx.x;
    int lane = threadIdx.x;
    __shared__ int sb[2];
    if (lane < 2) {
        int tgt = g + lane;
        int lo = 0, hi = N_NODES;
        while (lo < hi) { int m = (lo + hi) >> 1; if (batch[m] < tgt) lo = m + 1; else hi = m; }
        sb[lane] = lo;
    }
    __syncthreads();
    int s0 = sb[0], s1 = sb[1];
    const float2* pp = (const float2*)pnode;
    float p0 = 0.f, p1 = 0.f;
    for (int i = s0 + lane; i < s1; i += 64) {
        float2 v = pp[i];
        p0 += v.x;
        p1 += v.y;
    }
#pragma unroll
    for (int d = 32; d > 0; d >>= 1) {
        p0 += __shfl_xor(p0, d);
        p1 += __shfl_xor(p1, d);
    }
    if (lane == 0) {
        float inv = 1.f / fmaxf((float)(s1 - s0), 1.f);
        out[2 * g + 0] = p0 * inv + bl[0];
        out[2 * g + 1] = p1 * inv + bl[1];
    }
}

extern "C" void kernel_launch(void* const* d_in, const int* in_sizes, int n_in,
                              void* d_out, int out_size, void* d_ws, size_t ws_size,
                              hipStream_t stream) {
    const float* x  = (const float*)d_in[0];
    const int* ei   = (const int*)d_in[1];
    const int* batch = (const int*)d_in[2];
    const float* W1 = (const float*)d_in[3];
    const float* b1 = (const float*)d_in[4];
    const float* W2 = (const float*)d_in[5];
    const float* b2 = (const float*)d_in[6];
    const float* Wl = (const float*)d_in[7];
    const float* bl = (const float*)d_in[8];
    float* out = (float*)d_out;
    const int* src = ei;
    const int* dst = ei + N_EDGES;

    char* ws = (char*)d_ws;
    size_t o = 0;
    auto alloc = [&](size_t bytes) -> void* {
        o = (o + 255) & ~(size_t)255;
        void* p = ws + o;
        o += bytes;
        return p;
    };
    int* bcount = (int*)alloc((size_t)NBUCK * 4);
    int* bbase  = (int*)alloc((size_t)NBUCK * 4);
    int* bcur   = (int*)alloc((size_t)NBUCK * 4);
    float* dinv = (float*)alloc((size_t)(N_NODES + 1) * 4);  // +1 zero slot for tail
    int* offs   = (int*)alloc((size_t)(N_NODES + 1) * 4);
    unsigned short* wp1 = (unsigned short*)alloc(65536);
    unsigned short* wp2 = (unsigned short*)alloc(65536);
    float* pnode = (float*)alloc((size_t)N_NODES * 2 * 4);
    unsigned int* pairs = (unsigned int*)alloc((size_t)N_EDGES * 4);
    int* csr    = (int*)alloc((size_t)(N_EDGES + 8) * 4);               // +8 pad for unroll reads
    unsigned short* u = (unsigned short*)alloc((size_t)(N_NODES + 1) * 128 * 2);  // +1 zero row
    unsigned short* hh = (unsigned short*)alloc((size_t)N_NODES * 128 * 2);
    unsigned short* hl = (unsigned short*)alloc((size_t)N_NODES * 128 * 2);

    hipMemsetAsync(bcount, 0, (size_t)NBUCK * 4, stream);
    k_prep_hist<<<384, 256, 0, stream>>>(W1, W2, wp1, wp2, dst, bcount,
                                         (unsigned int*)(u + (size_t)N_NODES * 128), dinv);
    k_scan391<<<1, 512, 0, stream>>>(bcount, bbase, bcur, &offs[N_NODES]);
    k_bucket_g1<<<NBUCK + G1A, 256, 0, stream>>>(src, dst, bcur, pairs, x, wp1, u);
    k_bfill_g1<<<NBUCK + G1B, 256, 0, stream>>>(pairs, bbase, bcount, dinv, offs, csr, x, wp1, u);

    k_agg<<<(N_NODES + 3) / 4, 256, 0, stream>>>((const unsigned int*)u, offs, csr, dinv, b1,
                                                 (unsigned int*)hh, (unsigned int*)hl,
                                                 nullptr, nullptr);
    k_gemm_mfma_bf<<<NTILES, 256, 0, stream>>>(hh, hl, wp2, u);
    k_agg<<<(N_NODES + 3) / 4, 256, 0, stream>>>((const unsigned int*)u, offs, csr, dinv, b2,
                                                 nullptr, nullptr, Wl, pnode);

    k_fin<<<N_GRAPHS, 64, 0, stream>>>(pnode, batch, bl, out);
}

// Round 5
// 319.289 us; speedup vs baseline: 1.3528x; 1.0061x over previous
//
#include <hip/hip_runtime.h>
#include <hip/hip_bf16.h>

#define N_NODES 100000
#define N_EDGES 1600000
#define FEAT 128
#define N_GRAPHS 1024
#define NBUCK 391   // ceil(N_NODES/256) windows of 256 nodes (bucket = dst >> 8)
#define CHUNK 4096  // edges per k_bucket block
#define NTILES 1563 // ceil(N_NODES/64) gemm row tiles
#define G1A 781     // gemm1 tiles overlapped with bucket
#define G1B 782     // gemm1 tiles overlapped with bfill

typedef short short8 __attribute__((ext_vector_type(8)));
typedef float float4v __attribute__((ext_vector_type(4)));

static __device__ inline unsigned short f2bf(float f) {
    __hip_bfloat16 b = __float2bfloat16(f);
    unsigned short r;
    __builtin_memcpy(&r, &b, 2);
    return r;
}
static __device__ inline float bf_lo(unsigned int v) { return __uint_as_float(v << 16); }
static __device__ inline float bf_hi(unsigned int v) { return __uint_as_float(v & 0xFFFF0000u); }

// ---------------- dispatch 1: W-split prep (blocks 0..127) + dst histogram (blocks 128..383) ----------
__global__ __launch_bounds__(256) void k_prep_hist(const float* __restrict__ W1,
                                                   const float* __restrict__ W2,
                                                   unsigned short* __restrict__ wp1,
                                                   unsigned short* __restrict__ wp2,
                                                   const int* __restrict__ dst,
                                                   int* __restrict__ bcount,
                                                   unsigned int* __restrict__ udummy,
                                                   unsigned int* __restrict__ u2dummy,
                                                   float* __restrict__ dinv) {
    int bid = blockIdx.x;
    if (bid < 128) {
        const float* W = (bid < 64) ? W1 : W2;
        unsigned short* wp = (bid < 64) ? wp1 : wp2;
        int t = (bid & 63) * 256 + threadIdx.x;  // 0..16383
        int k = t >> 7, n = t & 127;
        float w = W[k * 128 + n];
        unsigned ub = __float_as_uint(w);
        unsigned short hi = (unsigned short)(ub >> 16);  // truncation split
        float hif = __uint_as_float(ub & 0xFFFF0000u);
        unsigned short lo = f2bf(w - hif);               // RNE residual
        int sidx = n * 128 + ((k & 7) | (8 * (((k >> 3) ^ n) & 15)));
        wp[sidx] = hi;
        wp[16384 + sidx] = lo;
        if (bid == 0) {
            if (threadIdx.x < 64) udummy[threadIdx.x] = 0;
            else if (threadIdx.x < 128) u2dummy[threadIdx.x - 64] = 0;
            else if (threadIdx.x == 128) dinv[N_NODES] = 0.f;
        }
    } else {
        __shared__ int h[NBUCK];
        for (int i = threadIdx.x; i < NBUCK; i += 256) h[i] = 0;
        __syncthreads();
        int hb = bid - 128;
        for (int e = hb * 256 + threadIdx.x; e < N_EDGES; e += 256 * 256)
            atomicAdd(&h[dst[e] >> 8], 1);
        __syncthreads();
        for (int i = threadIdx.x; i < NBUCK; i += 256) {
            int c = h[i];
            if (c) atomicAdd(&bcount[i], c);
        }
    }
}

// ---------------- dispatch 2: exclusive scan of 391 bucket counts (single block) ----------------
// bbase doubles as the CSR window base (wbase==bbase: per-bucket deg sum == bucket edge count).
__global__ __launch_bounds__(512) void k_scan391(const int* __restrict__ in,
                                                 int* __restrict__ base,
                                                 int* __restrict__ cur,
                                                 int* __restrict__ tail) {
    int t = threadIdx.x;
    int v = (t < NBUCK) ? in[t] : 0;
    int lane = t & 63, wid = t >> 6;
    int s = v;
#pragma unroll
    for (int d = 1; d < 64; d <<= 1) { int n = __shfl_up(s, d); if (lane >= d) s += n; }
    __shared__ int ws[8];
    if (lane == 63) ws[wid] = s;
    __syncthreads();
    if (t < 8) {
        int x = ws[t];
#pragma unroll
        for (int d = 1; d < 8; d <<= 1) { int n = __shfl_up(x, d); if ((int)t >= d) x += n; }
        ws[t] = x;
    }
    __syncthreads();
    int excl = s - v + (wid ? ws[wid - 1] : 0);
    if (t < NBUCK) {
        base[t] = excl;
        cur[t] = excl;
    }
    if (t == 0) tail[0] = N_EDGES;
}

// ---------------- shared gemm body: u = bf16(inp @ W) (UNSCALED — dinv applied in agg) ----------------
__device__ __forceinline__ void gemm_f32_body(int tile, const float* __restrict__ inp,
                                              const unsigned short* __restrict__ wp,
                                              unsigned short* __restrict__ u) {
    __shared__ unsigned short sW[32768];  // 64 KB: hi | lo (swizzled)
    {
        float4* d4 = (float4*)sW;
        const float4* s4 = (const float4*)wp;
#pragma unroll
        for (int i = 0; i < 16; ++i) d4[threadIdx.x + 256 * i] = s4[threadIdx.x + 256 * i];
    }
    __syncthreads();
    const int t = threadIdx.x;
    const int wv = t >> 6, L = t & 63;
    const int m = L & 15, q = L >> 4;
    const int r0 = tile * 64 + wv * 16;
    int arow = r0 + m;
    if (arow >= N_NODES) arow = N_NODES - 1;
    const float4* ap = (const float4*)(inp + (size_t)arow * 128);
    float4v acc[8];
#pragma unroll
    for (int c = 0; c < 8; ++c) acc[c] = (float4v){0.f, 0.f, 0.f, 0.f};
#pragma unroll
    for (int k0 = 0; k0 < 128; k0 += 32) {
        float4 f0 = ap[(k0 >> 2) + 2 * q];
        float4 f1 = ap[(k0 >> 2) + 2 * q + 1];
        float fa[8] = {f0.x, f0.y, f0.z, f0.w, f1.x, f1.y, f1.z, f1.w};
        short8 ah, al;
#pragma unroll
        for (int j = 0; j < 8; ++j) {
            unsigned ub = __float_as_uint(fa[j]);
            ah[j] = (short)(ub >> 16);
            float hif = __uint_as_float(ub & 0xFFFF0000u);
            al[j] = (short)f2bf(fa[j] - hif);
        }
        const int b = (k0 >> 3) + q;
#pragma unroll
        for (int c = 0; c < 8; ++c) {
            int ng = c * 16 + m;
            int elem = ng * 128 + 8 * ((b ^ ng) & 15);
            short8 bh = *(const short8*)&sW[elem];
            short8 bl = *(const short8*)&sW[16384 + elem];
            acc[c] = __builtin_amdgcn_mfma_f32_16x16x32_bf16(ah, bh, acc[c], 0, 0, 0);
            acc[c] = __builtin_amdgcn_mfma_f32_16x16x32_bf16(al, bh, acc[c], 0, 0, 0);
            acc[c] = __builtin_amdgcn_mfma_f32_16x16x32_bf16(ah, bl, acc[c], 0, 0, 0);
        }
    }
#pragma unroll
    for (int r = 0; r < 4; ++r) {
        int row = r0 + 4 * q + r;
        if (row < N_NODES) {
            unsigned short* up = u + (size_t)row * 128 + m;
#pragma unroll
            for (int c = 0; c < 8; ++c) up[c * 16] = f2bf(acc[c][r]);
        }
    }
}

// ---------------- dispatch 3: bucket binning (blocks 0..390) + gemm1 tiles 0..780 ----------------
__global__ __launch_bounds__(256) void k_bucket_g1(const int* __restrict__ src,
                                                   const int* __restrict__ dst,
                                                   int* __restrict__ bcur,
                                                   unsigned int* __restrict__ pairs,
                                                   const float* __restrict__ x,
                                                   const unsigned short* __restrict__ wp1,
                                                   unsigned short* __restrict__ u) {
    if (blockIdx.x >= NBUCK) {
        gemm_f32_body(blockIdx.x - NBUCK, x, wp1, u);
        return;
    }
    __shared__ int cnt[NBUCK];
    __shared__ int basebuf[NBUCK];
    int t = threadIdx.x;
    int e0 = blockIdx.x * CHUNK;
    for (int i = t; i < NBUCK; i += 256) cnt[i] = 0;
    __syncthreads();
    unsigned pk[16]; int bk[16];
#pragma unroll
    for (int j = 0; j < 16; ++j) {
        int e = e0 + j * 256 + t;
        if (e < N_EDGES) {
            int s = src[e], d = dst[e];
            bk[j] = d >> 8;
            pk[j] = ((unsigned)s << 8) | (unsigned)(d & 255);
            atomicAdd(&cnt[bk[j]], 1);
        } else bk[j] = -1;
    }
    __syncthreads();
    for (int i = t; i < NBUCK; i += 256) {
        int c = cnt[i];
        basebuf[i] = c ? atomicAdd(&bcur[i], c) : 0;
        cnt[i] = 0;
    }
    __syncthreads();
#pragma unroll
    for (int j = 0; j < 16; ++j) {
        if (bk[j] >= 0) {
            int p = basebuf[bk[j]] + atomicAdd(&cnt[bk[j]], 1);
            pairs[p] = pk[j];
        }
    }
}

// ---------------- dispatch 4: fused deg+dinv+offs+csr fill (blocks 0..390) + gemm1 tiles 781..1562 ----
__global__ __launch_bounds__(256) void k_bfill_g1(const unsigned int* __restrict__ pairs,
                                                  const int* __restrict__ bbase,
                                                  const int* __restrict__ bcount,
                                                  float* __restrict__ dinv,
                                                  int* __restrict__ offs,
                                                  int* __restrict__ csr,
                                                  const float* __restrict__ x,
                                                  const unsigned short* __restrict__ wp1,
                                                  unsigned short* __restrict__ u) {
    if (blockIdx.x >= NBUCK) {
        gemm_f32_body(blockIdx.x - NBUCK + G1A, x, wp1, u);
        return;
    }
    __shared__ int degl[256];
    __shared__ int lcur[256];
    __shared__ int ws[4];
    int b = blockIdx.x, t = threadIdx.x;
    degl[t] = 0;
    __syncthreads();
    int s0 = bbase[b], n = bcount[b];
    for (int i = t; i < n; i += 256) atomicAdd(&degl[pairs[s0 + i] & 255u], 1);
    __syncthreads();
    int node = b * 256 + t;
    int dv = degl[t];
    if (node < N_NODES) dinv[node] = rsqrtf((float)(dv + 1));  // +1 self-loop
    int lane = t & 63, wid = t >> 6;
    int s = dv;
#pragma unroll
    for (int d = 1; d < 64; d <<= 1) { int nn = __shfl_up(s, d); if (lane >= d) s += nn; }
    if (lane == 63) ws[wid] = s;
    __syncthreads();
    if (t < 4) {
        int xx = ws[t];
#pragma unroll
        for (int d = 1; d < 4; d <<= 1) { int nn = __shfl_up(xx, d); if ((int)t >= d) xx += nn; }
        ws[t] = xx;
    }
    __syncthreads();
    int excl = s - dv + (wid ? ws[wid - 1] : 0) + bbase[b];  // wbase == bbase
    if (node < N_NODES) offs[node] = excl;
    lcur[t] = excl;
    __syncthreads();
    for (int i = t; i < n; i += 256) {
        unsigned pr = pairs[s0 + i];
        int p = atomicAdd(&lcur[pr & 255u], 1);
        csr[p] = (int)(pr >> 8);
    }
}

// ---------------- fused agg1 + gemm2: u2 = bf16(relu(Ahat@u + b1) @ W2) ----------------
// 512 threads, 32 nodes/block (100000 = 3125*32 exact). LDS = 64K (W2 hi/lo) + 16K (h f32) = 80 KB
// -> 2 blocks/CU (16 waves/CU). Phase 1: each wave aggregates 4 nodes (same loop as k_agg2),
// stores f32 h rows to LDS with float4-group XOR swizzle (g ^ (row&7)) for conflict-free MFMA reads.
// Phase 2: 32x128 @ 128x128 via 16x16x32 MFMA, hi/lo split of h on the fly (identical math to the
// old hh/hl-plane -> k_gemm_mfma_bf path). Eliminates 51.2 MB write + 51.2 MB read + one dispatch.
__global__ __launch_bounds__(512) void k_agg1_g2(const unsigned int* __restrict__ u,
                                                 const int* __restrict__ offs,
                                                 const int* __restrict__ csr,
                                                 const float* __restrict__ dinv,
                                                 const float* __restrict__ bias,
                                                 const unsigned short* __restrict__ wp,
                                                 unsigned short* __restrict__ u2) {
    __shared__ unsigned short sW[32768];   // 64 KB W2 hi|lo (swizzled)
    __shared__ float hS[32 * 128];         // 16 KB h rows (float4-group XOR swizzle)
    {
        float4* d4 = (float4*)sW;
        const float4* s4 = (const float4*)wp;
#pragma unroll
        for (int i = 0; i < 8; ++i) d4[threadIdx.x + 512 * i] = s4[threadIdx.x + 512 * i];
    }
    const int w = threadIdx.x >> 6;
    const int lane = threadIdx.x & 63;
    const int base = blockIdx.x * 32;

    // ---- phase 1: aggregation (4 nodes per wave, sequential) ----
    for (int n = 0; n < 4; ++n) {
        const int row = 4 * w + n;
        const int node = base + row;  // always < N_NODES
        int p = __builtin_amdgcn_readfirstlane(offs[node]);
        int e = __builtin_amdgcn_readfirstlane(offs[node + 1]);
        float dsf = dinv[node];
        unsigned int self = u[(size_t)node * 64 + lane];
        float ax0 = dsf * bf_lo(self), ay0 = dsf * bf_hi(self);
        float ax1 = 0.f, ay1 = 0.f, ax2 = 0.f, ay2 = 0.f, ax3 = 0.f, ay3 = 0.f;
        float ax4 = 0.f, ay4 = 0.f, ax5 = 0.f, ay5 = 0.f, ax6 = 0.f, ay6 = 0.f;
        float ax7 = 0.f, ay7 = 0.f;
        for (; p < e; p += 8) {
            int c0 = csr[p + 0], c1 = csr[p + 1], c2 = csr[p + 2], c3 = csr[p + 3];
            int c4 = csr[p + 4], c5 = csr[p + 5], c6 = csr[p + 6], c7 = csr[p + 7];
            int i0 = c0;
            int i1 = (p + 1 < e) ? c1 : N_NODES;
            int i2 = (p + 2 < e) ? c2 : N_NODES;
            int i3 = (p + 3 < e) ? c3 : N_NODES;
            int i4 = (p + 4 < e) ? c4 : N_NODES;
            int i5 = (p + 5 < e) ? c5 : N_NODES;
            int i6 = (p + 6 < e) ? c6 : N_NODES;
            int i7 = (p + 7 < e) ? c7 : N_NODES;
            float d0 = dinv[i0], d1 = dinv[i1], d2 = dinv[i2], d3 = dinv[i3];
            float d4 = dinv[i4], d5 = dinv[i5], d6 = dinv[i6], d7 = dinv[i7];
            unsigned v0 = (u + (size_t)i0 * 64)[lane];
            unsigned v1 = (u + (size_t)i1 * 64)[lane];
            unsigned v2 = (u + (size_t)i2 * 64)[lane];
            unsigned v3 = (u + (size_t)i3 * 64)[lane];
            unsigned v4 = (u + (size_t)i4 * 64)[lane];
            unsigned v5 = (u + (size_t)i5 * 64)[lane];
            unsigned v6 = (u + (size_t)i6 * 64)[lane];
            unsigned v7 = (u + (size_t)i7 * 64)[lane];
            ax0 = fmaf(d0, bf_lo(v0), ax0); ay0 = fmaf(d0, bf_hi(v0), ay0);
            ax1 = fmaf(d1, bf_lo(v1), ax1); ay1 = fmaf(d1, bf_hi(v1), ay1);
            ax2 = fmaf(d2, bf_lo(v2), ax2); ay2 = fmaf(d2, bf_hi(v2), ay2);
            ax3 = fmaf(d3, bf_lo(v3), ax3); ay3 = fmaf(d3, bf_hi(v3), ay3);
            ax4 = fmaf(d4, bf_lo(v4), ax4); ay4 = fmaf(d4, bf_hi(v4), ay4);
            ax5 = fmaf(d5, bf_lo(v5), ax5); ay5 = fmaf(d5, bf_hi(v5), ay5);
            ax6 = fmaf(d6, bf_lo(v6), ax6); ay6 = fmaf(d6, bf_hi(v6), ay6);
            ax7 = fmaf(d7, bf_lo(v7), ax7); ay7 = fmaf(d7, bf_hi(v7), ay7);
        }
        float2 b = ((const float2*)bias)[lane];
        float sx = ((ax0 + ax1) + (ax2 + ax3)) + ((ax4 + ax5) + (ax6 + ax7));
        float sy = ((ay0 + ay1) + (ay2 + ay3)) + ((ay4 + ay5) + (ay6 + ay7));
        float r0 = fmaxf(dsf * sx + b.x, 0.f);
        float r1 = fmaxf(dsf * sy + b.y, 0.f);
        // swizzled LDS write: k = 2*lane -> float4-group g = lane>>1, phys group = g ^ (row&7)
        int g4 = (lane >> 1) ^ (row & 7);
        float2* hp = (float2*)&hS[row * 128 + g4 * 4 + (lane & 1) * 2];
        *hp = (float2){r0, r1};
    }
    __syncthreads();

    // ---- phase 2: u2[base..base+31] = bf16(h @ W2), 3-MFMA hi/lo scheme ----
    const int m = lane & 15, q = lane >> 4;
    const int rt = w >> 2;   // row-tile 0/1 (rows 16*rt..16*rt+15)
    const int cw = w & 3;    // column quarter (cols 32*cw..32*cw+31)
    const int arow = 16 * rt + m;
    float4v acc[2];
    acc[0] = (float4v){0.f, 0.f, 0.f, 0.f};
    acc[1] = (float4v){0.f, 0.f, 0.f, 0.f};
#pragma unroll
    for (int k0 = 0; k0 < 128; k0 += 32) {
        int g1 = (k0 >> 2) + 2 * q;
        float4 f0 = *(const float4*)&hS[arow * 128 + ((g1 ^ (arow & 7)) << 2)];
        float4 f1 = *(const float4*)&hS[arow * 128 + (((g1 + 1) ^ (arow & 7)) << 2)];
        float fa[8] = {f0.x, f0.y, f0.z, f0.w, f1.x, f1.y, f1.z, f1.w};
        short8 ah, al;
#pragma unroll
        for (int j = 0; j < 8; ++j) {
            unsigned ub = __float_as_uint(fa[j]);
            ah[j] = (short)(ub >> 16);
            float hif = __uint_as_float(ub & 0xFFFF0000u);
            al[j] = (short)f2bf(fa[j] - hif);
        }
        const int b = (k0 >> 3) + q;
#pragma unroll
        for (int cc = 0; cc < 2; ++cc) {
            int c = 2 * cw + cc;
            int ng = c * 16 + m;
            int elem = ng * 128 + 8 * ((b ^ ng) & 15);
            short8 bh = *(const short8*)&sW[elem];
            short8 bl = *(const short8*)&sW[16384 + elem];
            acc[cc] = __builtin_amdgcn_mfma_f32_16x16x32_bf16(ah, bh, acc[cc], 0, 0, 0);
            acc[cc] = __builtin_amdgcn_mfma_f32_16x16x32_bf16(al, bh, acc[cc], 0, 0, 0);
            acc[cc] = __builtin_amdgcn_mfma_f32_16x16x32_bf16(ah, bl, acc[cc], 0, 0, 0);
        }
    }
#pragma unroll
    for (int r = 0; r < 4; ++r) {
        int row = 16 * rt + 4 * q + r;
        unsigned short* up = u2 + (size_t)(base + row) * 128 + m;
        up[(2 * cw + 0) * 16] = f2bf(acc[0][r]);
        up[(2 * cw + 1) * 16] = f2bf(acc[1][r]);
    }
}

// ---------------- agg2 (layer 2, pool-fused): project h2 onto Wl, per-node partial to pnode ----
__global__ __launch_bounds__(256) void k_agg2(const unsigned int* __restrict__ u,
                                              const int* __restrict__ offs,
                                              const int* __restrict__ csr,
                                              const float* __restrict__ dinv,
                                              const float* __restrict__ bias,
                                              const float* __restrict__ Wl,
                                              float* __restrict__ pnode) {
    int wid = threadIdx.x >> 6;
    int lane = threadIdx.x & 63;
    int node = __builtin_amdgcn_readfirstlane(blockIdx.x * 4 + wid);
    if (node >= N_NODES) return;
    int p = __builtin_amdgcn_readfirstlane(offs[node]);
    int e = __builtin_amdgcn_readfirstlane(offs[node + 1]);
    float dsf = dinv[node];
    unsigned int self = u[(size_t)node * 64 + lane];
    float ax0 = dsf * bf_lo(self), ay0 = dsf * bf_hi(self);
    float ax1 = 0.f, ay1 = 0.f, ax2 = 0.f, ay2 = 0.f, ax3 = 0.f, ay3 = 0.f;
    float ax4 = 0.f, ay4 = 0.f, ax5 = 0.f, ay5 = 0.f, ax6 = 0.f, ay6 = 0.f;
    float ax7 = 0.f, ay7 = 0.f;
    for (; p < e; p += 8) {
        int c0 = csr[p + 0], c1 = csr[p + 1], c2 = csr[p + 2], c3 = csr[p + 3];
        int c4 = csr[p + 4], c5 = csr[p + 5], c6 = csr[p + 6], c7 = csr[p + 7];
        int i0 = c0;
        int i1 = (p + 1 < e) ? c1 : N_NODES;
        int i2 = (p + 2 < e) ? c2 : N_NODES;
        int i3 = (p + 3 < e) ? c3 : N_NODES;
        int i4 = (p + 4 < e) ? c4 : N_NODES;
        int i5 = (p + 5 < e) ? c5 : N_NODES;
        int i6 = (p + 6 < e) ? c6 : N_NODES;
        int i7 = (p + 7 < e) ? c7 : N_NODES;
        float d0 = dinv[i0], d1 = dinv[i1], d2 = dinv[i2], d3 = dinv[i3];
        float d4 = dinv[i4], d5 = dinv[i5], d6 = dinv[i6], d7 = dinv[i7];
        unsigned v0 = (u + (size_t)i0 * 64)[lane];
        unsigned v1 = (u + (size_t)i1 * 64)[lane];
        unsigned v2 = (u + (size_t)i2 * 64)[lane];
        unsigned v3 = (u + (size_t)i3 * 64)[lane];
        unsigned v4 = (u + (size_t)i4 * 64)[lane];
        unsigned v5 = (u + (size_t)i5 * 64)[lane];
        unsigned v6 = (u + (size_t)i6 * 64)[lane];
        unsigned v7 = (u + (size_t)i7 * 64)[lane];
        ax0 = fmaf(d0, bf_lo(v0), ax0); ay0 = fmaf(d0, bf_hi(v0), ay0);
        ax1 = fmaf(d1, bf_lo(v1), ax1); ay1 = fmaf(d1, bf_hi(v1), ay1);
        ax2 = fmaf(d2, bf_lo(v2), ax2); ay2 = fmaf(d2, bf_hi(v2), ay2);
        ax3 = fmaf(d3, bf_lo(v3), ax3); ay3 = fmaf(d3, bf_hi(v3), ay3);
        ax4 = fmaf(d4, bf_lo(v4), ax4); ay4 = fmaf(d4, bf_hi(v4), ay4);
        ax5 = fmaf(d5, bf_lo(v5), ax5); ay5 = fmaf(d5, bf_hi(v5), ay5);
        ax6 = fmaf(d6, bf_lo(v6), ax6); ay6 = fmaf(d6, bf_hi(v6), ay6);
        ax7 = fmaf(d7, bf_lo(v7), ax7); ay7 = fmaf(d7, bf_hi(v7), ay7);
    }
    float2 b = ((const float2*)bias)[lane];
    float sx = ((ax0 + ax1) + (ax2 + ax3)) + ((ax4 + ax5) + (ax6 + ax7));
    float sy = ((ay0 + ay1) + (ay2 + ay3)) + ((ay4 + ay5) + (ay6 + ay7));
    float r0 = fmaxf(dsf * sx + b.x, 0.f);
    float r1 = fmaxf(dsf * sy + b.y, 0.f);
    // fused pool projection: lane holds channels (2*lane, 2*lane+1); Wl row-major [128][2].
    float2 wl0 = ((const float2*)Wl)[2 * lane];
    float2 wl1 = ((const float2*)Wl)[2 * lane + 1];
    float p0 = r0 * wl0.x + r1 * wl1.x;
    float p1 = r0 * wl0.y + r1 * wl1.y;
#pragma unroll
    for (int d = 32; d > 0; d >>= 1) {
        p0 += __shfl_xor(p0, d);
        p1 += __shfl_xor(p1, d);
    }
    if (lane == 0) {
        float2* pp = (float2*)pnode;
        pp[node] = (float2){p0, p1};
    }
}

// ---------------- finalize: out[g] = segsum(pnode)/max(cnt,1) + bl (1 wave per graph) ----------
__global__ __launch_bounds__(64) void k_fin(const float* __restrict__ pnode,
                                            const int* __restrict__ batch,
                                            const float* __restrict__ bl,
                                            float* __restrict__ out) {
    int g = blockIdx.x;
    int lane = threadIdx.x;
    __shared__ int sb[2];
    if (lane < 2) {
        int tgt = g + lane;
        int lo = 0, hi = N_NODES;
        while (lo < hi) { int m = (lo + hi) >> 1; if (batch[m] < tgt) lo = m + 1; else hi = m; }
        sb[lane] = lo;
    }
    __syncthreads();
    int s0 = sb[0], s1 = sb[1];
    const float2* pp = (const float2*)pnode;
    float p0 = 0.f, p1 = 0.f;
    for (int i = s0 + lane; i < s1; i += 64) {
        float2 v = pp[i];
        p0 += v.x;
        p1 += v.y;
    }
#pragma unroll
    for (int d = 32; d > 0; d >>= 1) {
        p0 += __shfl_xor(p0, d);
        p1 += __shfl_xor(p1, d);
    }
    if (lane == 0) {
        float inv = 1.f / fmaxf((float)(s1 - s0), 1.f);
        out[2 * g + 0] = p0 * inv + bl[0];
        out[2 * g + 1] = p1 * inv + bl[1];
    }
}

extern "C" void kernel_launch(void* const* d_in, const int* in_sizes, int n_in,
                              void* d_out, int out_size, void* d_ws, size_t ws_size,
                              hipStream_t stream) {
    const float* x  = (const float*)d_in[0];
    const int* ei   = (const int*)d_in[1];
    const int* batch = (const int*)d_in[2];
    const float* W1 = (const float*)d_in[3];
    const float* b1 = (const float*)d_in[4];
    const float* W2 = (const float*)d_in[5];
    const float* b2 = (const float*)d_in[6];
    const float* Wl = (const float*)d_in[7];
    const float* bl = (const float*)d_in[8];
    float* out = (float*)d_out;
    const int* src = ei;
    const int* dst = ei + N_EDGES;

    char* ws = (char*)d_ws;
    size_t o = 0;
    auto alloc = [&](size_t bytes) -> void* {
        o = (o + 255) & ~(size_t)255;
        void* p = ws + o;
        o += bytes;
        return p;
    };
    int* bcount = (int*)alloc((size_t)NBUCK * 4);
    int* bbase  = (int*)alloc((size_t)NBUCK * 4);
    int* bcur   = (int*)alloc((size_t)NBUCK * 4);
    float* dinv = (float*)alloc((size_t)(N_NODES + 1) * 4);  // +1 zero slot for tail
    int* offs   = (int*)alloc((size_t)(N_NODES + 1) * 4);
    unsigned short* wp1 = (unsigned short*)alloc(65536);
    unsigned short* wp2 = (unsigned short*)alloc(65536);
    float* pnode = (float*)alloc((size_t)N_NODES * 2 * 4);
    unsigned int* pairs = (unsigned int*)alloc((size_t)N_EDGES * 4);
    int* csr    = (int*)alloc((size_t)(N_EDGES + 8) * 4);               // +8 pad for unroll reads
    unsigned short* u  = (unsigned short*)alloc((size_t)(N_NODES + 1) * 128 * 2);  // +1 zero row
    unsigned short* u2 = (unsigned short*)alloc((size_t)(N_NODES + 1) * 128 * 2);  // +1 zero row

    hipMemsetAsync(bcount, 0, (size_t)NBUCK * 4, stream);
    k_prep_hist<<<384, 256, 0, stream>>>(W1, W2, wp1, wp2, dst, bcount,
                                         (unsigned int*)(u + (size_t)N_NODES * 128),
                                         (unsigned int*)(u2 + (size_t)N_NODES * 128), dinv);
    k_scan391<<<1, 512, 0, stream>>>(bcount, bbase, bcur, &offs[N_NODES]);
    k_bucket_g1<<<NBUCK + G1A, 256, 0, stream>>>(src, dst, bcur, pairs, x, wp1, u);
    k_bfill_g1<<<NBUCK + G1B, 256, 0, stream>>>(pairs, bbase, bcount, dinv, offs, csr, x, wp1, u);

    k_agg1_g2<<<N_NODES / 32, 512, 0, stream>>>((const unsigned int*)u, offs, csr, dinv, b1,
                                                wp2, u2);
    k_agg2<<<(N_NODES + 3) / 4, 256, 0, stream>>>((const unsigned int*)u2, offs, csr, dinv, b2,
                                                  Wl, pnode);

    k_fin<<<N_GRAPHS, 64, 0, stream>>>(pnode, batch, bl, out);
}

// Round 6
// 318.332 us; speedup vs baseline: 1.3569x; 1.0030x over previous
//
#include <hip/hip_runtime.h>
#include <hip/hip_bf16.h>

#define N_NODES 100000
#define N_EDGES 1600000
#define FEAT 128
#define N_GRAPHS 1024
#define NBUCK 391   // ceil(N_NODES/256) windows of 256 nodes (bucket = dst >> 8)
#define CHUNK 4096  // edges per k_bucket block
#define NTILES 1563 // ceil(N_NODES/64) gemm row tiles
#define G1A 781     // gemm1 tiles overlapped with bucket
#define G1B 782     // gemm1 tiles overlapped with bfill

typedef short short8 __attribute__((ext_vector_type(8)));
typedef float float4v __attribute__((ext_vector_type(4)));

static __device__ inline unsigned short f2bf(float f) {
    __hip_bfloat16 b = __float2bfloat16(f);
    unsigned short r;
    __builtin_memcpy(&r, &b, 2);
    return r;
}
static __device__ inline float bf_lo(unsigned int v) { return __uint_as_float(v << 16); }
static __device__ inline float bf_hi(unsigned int v) { return __uint_as_float(v & 0xFFFF0000u); }

// ---------------- dispatch 1: W-split prep (blocks 0..127) + dst histogram (blocks 128..383) ----------
__global__ __launch_bounds__(256) void k_prep_hist(const float* __restrict__ W1,
                                                   const float* __restrict__ W2,
                                                   unsigned short* __restrict__ wp1,
                                                   unsigned short* __restrict__ wp2,
                                                   const int* __restrict__ dst,
                                                   int* __restrict__ bcount,
                                                   unsigned int* __restrict__ udummy,
                                                   unsigned int* __restrict__ u2dummy,
                                                   float* __restrict__ dinv) {
    int bid = blockIdx.x;
    if (bid < 128) {
        const float* W = (bid < 64) ? W1 : W2;
        unsigned short* wp = (bid < 64) ? wp1 : wp2;
        int t = (bid & 63) * 256 + threadIdx.x;  // 0..16383
        int k = t >> 7, n = t & 127;
        float w = W[k * 128 + n];
        unsigned ub = __float_as_uint(w);
        unsigned short hi = (unsigned short)(ub >> 16);  // truncation split
        float hif = __uint_as_float(ub & 0xFFFF0000u);
        unsigned short lo = f2bf(w - hif);               // RNE residual
        int sidx = n * 128 + ((k & 7) | (8 * (((k >> 3) ^ n) & 15)));
        wp[sidx] = hi;
        wp[16384 + sidx] = lo;
        if (bid == 0) {
            if (threadIdx.x < 64) udummy[threadIdx.x] = 0;
            else if (threadIdx.x < 128) u2dummy[threadIdx.x - 64] = 0;
            else if (threadIdx.x == 128) dinv[N_NODES] = 0.f;
        }
    } else {
        __shared__ int h[NBUCK];
        for (int i = threadIdx.x; i < NBUCK; i += 256) h[i] = 0;
        __syncthreads();
        int hb = bid - 128;
        for (int e = hb * 256 + threadIdx.x; e < N_EDGES; e += 256 * 256)
            atomicAdd(&h[dst[e] >> 8], 1);
        __syncthreads();
        for (int i = threadIdx.x; i < NBUCK; i += 256) {
            int c = h[i];
            if (c) atomicAdd(&bcount[i], c);
        }
    }
}

// ---------------- dispatch 2: exclusive scan of 391 bucket counts (single block) ----------------
// bbase doubles as the CSR window base (wbase==bbase: per-bucket deg sum == bucket edge count).
__global__ __launch_bounds__(512) void k_scan391(const int* __restrict__ in,
                                                 int* __restrict__ base,
                                                 int* __restrict__ cur,
                                                 int* __restrict__ tail) {
    int t = threadIdx.x;
    int v = (t < NBUCK) ? in[t] : 0;
    int lane = t & 63, wid = t >> 6;
    int s = v;
#pragma unroll
    for (int d = 1; d < 64; d <<= 1) { int n = __shfl_up(s, d); if (lane >= d) s += n; }
    __shared__ int ws[8];
    if (lane == 63) ws[wid] = s;
    __syncthreads();
    if (t < 8) {
        int x = ws[t];
#pragma unroll
        for (int d = 1; d < 8; d <<= 1) { int n = __shfl_up(x, d); if ((int)t >= d) x += n; }
        ws[t] = x;
    }
    __syncthreads();
    int excl = s - v + (wid ? ws[wid - 1] : 0);
    if (t < NBUCK) {
        base[t] = excl;
        cur[t] = excl;
    }
    if (t == 0) tail[0] = N_EDGES;
}

// ---------------- shared gemm body: u = bf16(inp @ W) (UNSCALED — dinv applied in agg) ----------------
__device__ __forceinline__ void gemm_f32_body(int tile, const float* __restrict__ inp,
                                              const unsigned short* __restrict__ wp,
                                              unsigned short* __restrict__ u) {
    __shared__ unsigned short sW[32768];  // 64 KB: hi | lo (swizzled)
    {
        float4* d4 = (float4*)sW;
        const float4* s4 = (const float4*)wp;
#pragma unroll
        for (int i = 0; i < 16; ++i) d4[threadIdx.x + 256 * i] = s4[threadIdx.x + 256 * i];
    }
    __syncthreads();
    const int t = threadIdx.x;
    const int wv = t >> 6, L = t & 63;
    const int m = L & 15, q = L >> 4;
    const int r0 = tile * 64 + wv * 16;
    int arow = r0 + m;
    if (arow >= N_NODES) arow = N_NODES - 1;
    const float4* ap = (const float4*)(inp + (size_t)arow * 128);
    float4v acc[8];
#pragma unroll
    for (int c = 0; c < 8; ++c) acc[c] = (float4v){0.f, 0.f, 0.f, 0.f};
#pragma unroll
    for (int k0 = 0; k0 < 128; k0 += 32) {
        float4 f0 = ap[(k0 >> 2) + 2 * q];
        float4 f1 = ap[(k0 >> 2) + 2 * q + 1];
        float fa[8] = {f0.x, f0.y, f0.z, f0.w, f1.x, f1.y, f1.z, f1.w};
        short8 ah, al;
#pragma unroll
        for (int j = 0; j < 8; ++j) {
            unsigned ub = __float_as_uint(fa[j]);
            ah[j] = (short)(ub >> 16);
            float hif = __uint_as_float(ub & 0xFFFF0000u);
            al[j] = (short)f2bf(fa[j] - hif);
        }
        const int b = (k0 >> 3) + q;
#pragma unroll
        for (int c = 0; c < 8; ++c) {
            int ng = c * 16 + m;
            int elem = ng * 128 + 8 * ((b ^ ng) & 15);
            short8 bh = *(const short8*)&sW[elem];
            short8 bl = *(const short8*)&sW[16384 + elem];
            acc[c] = __builtin_amdgcn_mfma_f32_16x16x32_bf16(ah, bh, acc[c], 0, 0, 0);
            acc[c] = __builtin_amdgcn_mfma_f32_16x16x32_bf16(al, bh, acc[c], 0, 0, 0);
            acc[c] = __builtin_amdgcn_mfma_f32_16x16x32_bf16(ah, bl, acc[c], 0, 0, 0);
        }
    }
#pragma unroll
    for (int r = 0; r < 4; ++r) {
        int row = r0 + 4 * q + r;
        if (row < N_NODES) {
            unsigned short* up = u + (size_t)row * 128 + m;
#pragma unroll
            for (int c = 0; c < 8; ++c) up[c * 16] = f2bf(acc[c][r]);
        }
    }
}

// ---------------- dispatch 3: bucket binning (blocks 0..390) + gemm1 tiles 0..780 ----------------
__global__ __launch_bounds__(256) void k_bucket_g1(const int* __restrict__ src,
                                                   const int* __restrict__ dst,
                                                   int* __restrict__ bcur,
                                                   unsigned int* __restrict__ pairs,
                                                   const float* __restrict__ x,
                                                   const unsigned short* __restrict__ wp1,
                                                   unsigned short* __restrict__ u) {
    if (blockIdx.x >= NBUCK) {
        gemm_f32_body(blockIdx.x - NBUCK, x, wp1, u);
        return;
    }
    __shared__ int cnt[NBUCK];
    __shared__ int basebuf[NBUCK];
    int t = threadIdx.x;
    int e0 = blockIdx.x * CHUNK;
    for (int i = t; i < NBUCK; i += 256) cnt[i] = 0;
    __syncthreads();
    unsigned pk[16]; int bk[16];
#pragma unroll
    for (int j = 0; j < 16; ++j) {
        int e = e0 + j * 256 + t;
        if (e < N_EDGES) {
            int s = src[e], d = dst[e];
            bk[j] = d >> 8;
            pk[j] = ((unsigned)s << 8) | (unsigned)(d & 255);
            atomicAdd(&cnt[bk[j]], 1);
        } else bk[j] = -1;
    }
    __syncthreads();
    for (int i = t; i < NBUCK; i += 256) {
        int c = cnt[i];
        basebuf[i] = c ? atomicAdd(&bcur[i], c) : 0;
        cnt[i] = 0;
    }
    __syncthreads();
#pragma unroll
    for (int j = 0; j < 16; ++j) {
        if (bk[j] >= 0) {
            int p = basebuf[bk[j]] + atomicAdd(&cnt[bk[j]], 1);
            pairs[p] = pk[j];
        }
    }
}

// ---------------- dispatch 4: fused deg+dinv+offs+csr fill (blocks 0..390) + gemm1 tiles 781..1562 ----
__global__ __launch_bounds__(256) void k_bfill_g1(const unsigned int* __restrict__ pairs,
                                                  const int* __restrict__ bbase,
                                                  const int* __restrict__ bcount,
                                                  float* __restrict__ dinv,
                                                  int* __restrict__ offs,
                                                  int* __restrict__ csr,
                                                  const float* __restrict__ x,
                                                  const unsigned short* __restrict__ wp1,
                                                  unsigned short* __restrict__ u) {
    if (blockIdx.x >= NBUCK) {
        gemm_f32_body(blockIdx.x - NBUCK + G1A, x, wp1, u);
        return;
    }
    __shared__ int degl[256];
    __shared__ int lcur[256];
    __shared__ int ws[4];
    int b = blockIdx.x, t = threadIdx.x;
    degl[t] = 0;
    __syncthreads();
    int s0 = bbase[b], n = bcount[b];
    for (int i = t; i < n; i += 256) atomicAdd(&degl[pairs[s0 + i] & 255u], 1);
    __syncthreads();
    int node = b * 256 + t;
    int dv = degl[t];
    if (node < N_NODES) dinv[node] = rsqrtf((float)(dv + 1));  // +1 self-loop
    int lane = t & 63, wid = t >> 6;
    int s = dv;
#pragma unroll
    for (int d = 1; d < 64; d <<= 1) { int nn = __shfl_up(s, d); if (lane >= d) s += nn; }
    if (lane == 63) ws[wid] = s;
    __syncthreads();
    if (t < 4) {
        int xx = ws[t];
#pragma unroll
        for (int d = 1; d < 4; d <<= 1) { int nn = __shfl_up(xx, d); if ((int)t >= d) xx += nn; }
        ws[t] = xx;
    }
    __syncthreads();
    int excl = s - dv + (wid ? ws[wid - 1] : 0) + bbase[b];  // wbase == bbase
    if (node < N_NODES) offs[node] = excl;
    lcur[t] = excl;
    __syncthreads();
    for (int i = t; i < n; i += 256) {
        unsigned pr = pairs[s0 + i];
        int p = atomicAdd(&lcur[pr & 255u], 1);
        csr[p] = (int)(pr >> 8);
    }
}

// ---------------- fused agg1 + gemm2: u2 = bf16(relu(Ahat@u + b1) @ W2) ----------------
// 512 threads, 32 nodes/block (100000 = 3125*32 exact).
// R5 fix: W2 is NOT staged in LDS (64 KB tile capped CU at 2 blocks -> 38% occupancy starved the
// latency-bound gather, 93us). Phase 2 reads W2 hi/lo fragments straight from global (64 KB,
// L2-resident across all 3125 blocks; elem indexing identical to the old sW copy). LDS = 16 KB
// (h rows only) -> 3 blocks/CU at launch_bounds(512,6) (VGPR cap 85), ~75% occupancy.
__global__ __launch_bounds__(512, 6) void k_agg1_g2(const unsigned int* __restrict__ u,
                                                    const int* __restrict__ offs,
                                                    const int* __restrict__ csr,
                                                    const float* __restrict__ dinv,
                                                    const float* __restrict__ bias,
                                                    const unsigned short* __restrict__ wp,
                                                    unsigned short* __restrict__ u2) {
    __shared__ float hS[32 * 128];         // 16 KB h rows (float4-group XOR swizzle)
    const int w = threadIdx.x >> 6;
    const int lane = threadIdx.x & 63;
    const int base = blockIdx.x * 32;

    // ---- phase 1: aggregation (4 nodes per wave, sequential) ----
    for (int n = 0; n < 4; ++n) {
        const int row = 4 * w + n;
        const int node = base + row;  // always < N_NODES
        int p = __builtin_amdgcn_readfirstlane(offs[node]);
        int e = __builtin_amdgcn_readfirstlane(offs[node + 1]);
        float dsf = dinv[node];
        unsigned int self = u[(size_t)node * 64 + lane];
        float ax0 = dsf * bf_lo(self), ay0 = dsf * bf_hi(self);
        float ax1 = 0.f, ay1 = 0.f, ax2 = 0.f, ay2 = 0.f, ax3 = 0.f, ay3 = 0.f;
        float ax4 = 0.f, ay4 = 0.f, ax5 = 0.f, ay5 = 0.f, ax6 = 0.f, ay6 = 0.f;
        float ax7 = 0.f, ay7 = 0.f;
        for (; p < e; p += 8) {
            int c0 = csr[p + 0], c1 = csr[p + 1], c2 = csr[p + 2], c3 = csr[p + 3];
            int c4 = csr[p + 4], c5 = csr[p + 5], c6 = csr[p + 6], c7 = csr[p + 7];
            int i0 = c0;
            int i1 = (p + 1 < e) ? c1 : N_NODES;
            int i2 = (p + 2 < e) ? c2 : N_NODES;
            int i3 = (p + 3 < e) ? c3 : N_NODES;
            int i4 = (p + 4 < e) ? c4 : N_NODES;
            int i5 = (p + 5 < e) ? c5 : N_NODES;
            int i6 = (p + 6 < e) ? c6 : N_NODES;
            int i7 = (p + 7 < e) ? c7 : N_NODES;
            float d0 = dinv[i0], d1 = dinv[i1], d2 = dinv[i2], d3 = dinv[i3];
            float d4 = dinv[i4], d5 = dinv[i5], d6 = dinv[i6], d7 = dinv[i7];
            unsigned v0 = (u + (size_t)i0 * 64)[lane];
            unsigned v1 = (u + (size_t)i1 * 64)[lane];
            unsigned v2 = (u + (size_t)i2 * 64)[lane];
            unsigned v3 = (u + (size_t)i3 * 64)[lane];
            unsigned v4 = (u + (size_t)i4 * 64)[lane];
            unsigned v5 = (u + (size_t)i5 * 64)[lane];
            unsigned v6 = (u + (size_t)i6 * 64)[lane];
            unsigned v7 = (u + (size_t)i7 * 64)[lane];
            ax0 = fmaf(d0, bf_lo(v0), ax0); ay0 = fmaf(d0, bf_hi(v0), ay0);
            ax1 = fmaf(d1, bf_lo(v1), ax1); ay1 = fmaf(d1, bf_hi(v1), ay1);
            ax2 = fmaf(d2, bf_lo(v2), ax2); ay2 = fmaf(d2, bf_hi(v2), ay2);
            ax3 = fmaf(d3, bf_lo(v3), ax3); ay3 = fmaf(d3, bf_hi(v3), ay3);
            ax4 = fmaf(d4, bf_lo(v4), ax4); ay4 = fmaf(d4, bf_hi(v4), ay4);
            ax5 = fmaf(d5, bf_lo(v5), ax5); ay5 = fmaf(d5, bf_hi(v5), ay5);
            ax6 = fmaf(d6, bf_lo(v6), ax6); ay6 = fmaf(d6, bf_hi(v6), ay6);
            ax7 = fmaf(d7, bf_lo(v7), ax7); ay7 = fmaf(d7, bf_hi(v7), ay7);
        }
        float2 b = ((const float2*)bias)[lane];
        float sx = ((ax0 + ax1) + (ax2 + ax3)) + ((ax4 + ax5) + (ax6 + ax7));
        float sy = ((ay0 + ay1) + (ay2 + ay3)) + ((ay4 + ay5) + (ay6 + ay7));
        float r0 = fmaxf(dsf * sx + b.x, 0.f);
        float r1 = fmaxf(dsf * sy + b.y, 0.f);
        // swizzled LDS write: k = 2*lane -> float4-group g = lane>>1, phys group = g ^ (row&7)
        int g4 = (lane >> 1) ^ (row & 7);
        float2* hp = (float2*)&hS[row * 128 + g4 * 4 + (lane & 1) * 2];
        *hp = (float2){r0, r1};
    }
    __syncthreads();

    // ---- phase 2: u2[base..base+31] = bf16(h @ W2), 3-MFMA hi/lo scheme; W2 from global ----
    const int m = lane & 15, q = lane >> 4;
    const int rt = w >> 2;   // row-tile 0/1 (rows 16*rt..16*rt+15)
    const int cw = w & 3;    // column quarter (cols 32*cw..32*cw+31)
    const int arow = 16 * rt + m;
    float4v acc[2];
    acc[0] = (float4v){0.f, 0.f, 0.f, 0.f};
    acc[1] = (float4v){0.f, 0.f, 0.f, 0.f};
#pragma unroll
    for (int k0 = 0; k0 < 128; k0 += 32) {
        int g1 = (k0 >> 2) + 2 * q;
        float4 f0 = *(const float4*)&hS[arow * 128 + ((g1 ^ (arow & 7)) << 2)];
        float4 f1 = *(const float4*)&hS[arow * 128 + (((g1 + 1) ^ (arow & 7)) << 2)];
        float fa[8] = {f0.x, f0.y, f0.z, f0.w, f1.x, f1.y, f1.z, f1.w};
        short8 ah, al;
#pragma unroll
        for (int j = 0; j < 8; ++j) {
            unsigned ub = __float_as_uint(fa[j]);
            ah[j] = (short)(ub >> 16);
            float hif = __uint_as_float(ub & 0xFFFF0000u);
            al[j] = (short)f2bf(fa[j] - hif);
        }
        const int b = (k0 >> 3) + q;
#pragma unroll
        for (int cc = 0; cc < 2; ++cc) {
            int c = 2 * cw + cc;
            int ng = c * 16 + m;
            int elem = ng * 128 + 8 * ((b ^ ng) & 15);
            short8 bh = *(const short8*)&wp[elem];
            short8 bl = *(const short8*)&wp[16384 + elem];
            acc[cc] = __builtin_amdgcn_mfma_f32_16x16x32_bf16(ah, bh, acc[cc], 0, 0, 0);
            acc[cc] = __builtin_amdgcn_mfma_f32_16x16x32_bf16(al, bh, acc[cc], 0, 0, 0);
            acc[cc] = __builtin_amdgcn_mfma_f32_16x16x32_bf16(ah, bl, acc[cc], 0, 0, 0);
        }
    }
#pragma unroll
    for (int r = 0; r < 4; ++r) {
        int row = 16 * rt + 4 * q + r;
        unsigned short* up = u2 + (size_t)(base + row) * 128 + m;
        up[(2 * cw + 0) * 16] = f2bf(acc[0][r]);
        up[(2 * cw + 1) * 16] = f2bf(acc[1][r]);
    }
}

// ---------------- agg2 (layer 2, pool-fused): project h2 onto Wl, per-node partial to pnode ----
__global__ __launch_bounds__(256) void k_agg2(const unsigned int* __restrict__ u,
                                              const int* __restrict__ offs,
                                              const int* __restrict__ csr,
                                              const float* __restrict__ dinv,
                                              const float* __restrict__ bias,
                                              const float* __restrict__ Wl,
                                              float* __restrict__ pnode) {
    int wid = threadIdx.x >> 6;
    int lane = threadIdx.x & 63;
    int node = __builtin_amdgcn_readfirstlane(blockIdx.x * 4 + wid);
    if (node >= N_NODES) return;
    int p = __builtin_amdgcn_readfirstlane(offs[node]);
    int e = __builtin_amdgcn_readfirstlane(offs[node + 1]);
    float dsf = dinv[node];
    unsigned int self = u[(size_t)node * 64 + lane];
    float ax0 = dsf * bf_lo(self), ay0 = dsf * bf_hi(self);
    float ax1 = 0.f, ay1 = 0.f, ax2 = 0.f, ay2 = 0.f, ax3 = 0.f, ay3 = 0.f;
    float ax4 = 0.f, ay4 = 0.f, ax5 = 0.f, ay5 = 0.f, ax6 = 0.f, ay6 = 0.f;
    float ax7 = 0.f, ay7 = 0.f;
    for (; p < e; p += 8) {
        int c0 = csr[p + 0], c1 = csr[p + 1], c2 = csr[p + 2], c3 = csr[p + 3];
        int c4 = csr[p + 4], c5 = csr[p + 5], c6 = csr[p + 6], c7 = csr[p + 7];
        int i0 = c0;
        int i1 = (p + 1 < e) ? c1 : N_NODES;
        int i2 = (p + 2 < e) ? c2 : N_NODES;
        int i3 = (p + 3 < e) ? c3 : N_NODES;
        int i4 = (p + 4 < e) ? c4 : N_NODES;
        int i5 = (p + 5 < e) ? c5 : N_NODES;
        int i6 = (p + 6 < e) ? c6 : N_NODES;
        int i7 = (p + 7 < e) ? c7 : N_NODES;
        float d0 = dinv[i0], d1 = dinv[i1], d2 = dinv[i2], d3 = dinv[i3];
        float d4 = dinv[i4], d5 = dinv[i5], d6 = dinv[i6], d7 = dinv[i7];
        unsigned v0 = (u + (size_t)i0 * 64)[lane];
        unsigned v1 = (u + (size_t)i1 * 64)[lane];
        unsigned v2 = (u + (size_t)i2 * 64)[lane];
        unsigned v3 = (u + (size_t)i3 * 64)[lane];
        unsigned v4 = (u + (size_t)i4 * 64)[lane];
        unsigned v5 = (u + (size_t)i5 * 64)[lane];
        unsigned v6 = (u + (size_t)i6 * 64)[lane];
        unsigned v7 = (u + (size_t)i7 * 64)[lane];
        ax0 = fmaf(d0, bf_lo(v0), ax0); ay0 = fmaf(d0, bf_hi(v0), ay0);
        ax1 = fmaf(d1, bf_lo(v1), ax1); ay1 = fmaf(d1, bf_hi(v1), ay1);
        ax2 = fmaf(d2, bf_lo(v2), ax2); ay2 = fmaf(d2, bf_hi(v2), ay2);
        ax3 = fmaf(d3, bf_lo(v3), ax3); ay3 = fmaf(d3, bf_hi(v3), ay3);
        ax4 = fmaf(d4, bf_lo(v4), ax4); ay4 = fmaf(d4, bf_hi(v4), ay4);
        ax5 = fmaf(d5, bf_lo(v5), ax5); ay5 = fmaf(d5, bf_hi(v5), ay5);
        ax6 = fmaf(d6, bf_lo(v6), ax6); ay6 = fmaf(d6, bf_hi(v6), ay6);
        ax7 = fmaf(d7, bf_lo(v7), ax7); ay7 = fmaf(d7, bf_hi(v7), ay7);
    }
    float2 b = ((const float2*)bias)[lane];
    float sx = ((ax0 + ax1) + (ax2 + ax3)) + ((ax4 + ax5) + (ax6 + ax7));
    float sy = ((ay0 + ay1) + (ay2 + ay3)) + ((ay4 + ay5) + (ay6 + ay7));
    float r0 = fmaxf(dsf * sx + b.x, 0.f);
    float r1 = fmaxf(dsf * sy + b.y, 0.f);
    // fused pool projection: lane holds channels (2*lane, 2*lane+1); Wl row-major [128][2].
    float2 wl0 = ((const float2*)Wl)[2 * lane];
    float2 wl1 = ((const float2*)Wl)[2 * lane + 1];
    float p0 = r0 * wl0.x + r1 * wl1.x;
    float p1 = r0 * wl0.y + r1 * wl1.y;
#pragma unroll
    for (int d = 32; d > 0; d >>= 1) {
        p0 += __shfl_xor(p0, d);
        p1 += __shfl_xor(p1, d);
    }
    if (lane == 0) {
        float2* pp = (float2*)pnode;
        pp[node] = (float2){p0, p1};
    }
}

// ---------------- finalize: out[g] = segsum(pnode)/max(cnt,1) + bl (1 wave per graph) ----------
__global__ __launch_bounds__(64) void k_fin(const float* __restrict__ pnode,
                                            const int* __restrict__ batch,
                                            const float* __restrict__ bl,
                                            float* __restrict__ out) {
    int g = blockIdx.x;
    int lane = threadIdx.x;
    __shared__ int sb[2];
    if (lane < 2) {
        int tgt = g + lane;
        int lo = 0, hi = N_NODES;
        while (lo < hi) { int m = (lo + hi) >> 1; if (batch[m] < tgt) lo = m + 1; else hi = m; }
        sb[lane] = lo;
    }
    __syncthreads();
    int s0 = sb[0], s1 = sb[1];
    const float2* pp = (const float2*)pnode;
    float p0 = 0.f, p1 = 0.f;
    for (int i = s0 + lane; i < s1; i += 64) {
        float2 v = pp[i];
        p0 += v.x;
        p1 += v.y;
    }
#pragma unroll
    for (int d = 32; d > 0; d >>= 1) {
        p0 += __shfl_xor(p0, d);
        p1 += __shfl_xor(p1, d);
    }
    if (lane == 0) {
        float inv = 1.f / fmaxf((float)(s1 - s0), 1.f);
        out[2 * g + 0] = p0 * inv + bl[0];
        out[2 * g + 1] = p1 * inv + bl[1];
    }
}

extern "C" void kernel_launch(void* const* d_in, const int* in_sizes, int n_in,
                              void* d_out, int out_size, void* d_ws, size_t ws_size,
                              hipStream_t stream) {
    const float* x  = (const float*)d_in[0];
    const int* ei   = (const int*)d_in[1];
    const int* batch = (const int*)d_in[2];
    const float* W1 = (const float*)d_in[3];
    const float* b1 = (const float*)d_in[4];
    const float* W2 = (const float*)d_in[5];
    const float* b2 = (const float*)d_in[6];
    const float* Wl = (const float*)d_in[7];
    const float* bl = (const float*)d_in[8];
    float* out = (float*)d_out;
    const int* src = ei;
    const int* dst = ei + N_EDGES;

    char* ws = (char*)d_ws;
    size_t o = 0;
    auto alloc = [&](size_t bytes) -> void* {
        o = (o + 255) & ~(size_t)255;
        void* p = ws + o;
        o += bytes;
        return p;
    };
    int* bcount = (int*)alloc((size_t)NBUCK * 4);
    int* bbase  = (int*)alloc((size_t)NBUCK * 4);
    int* bcur   = (int*)alloc((size_t)NBUCK * 4);
    float* dinv = (float*)alloc((size_t)(N_NODES + 1) * 4);  // +1 zero slot for tail
    int* offs   = (int*)alloc((size_t)(N_NODES + 1) * 4);
    unsigned short* wp1 = (unsigned short*)alloc(65536);
    unsigned short* wp2 = (unsigned short*)alloc(65536);
    float* pnode = (float*)alloc((size_t)N_NODES * 2 * 4);
    unsigned int* pairs = (unsigned int*)alloc((size_t)N_EDGES * 4);
    int* csr    = (int*)alloc((size_t)(N_EDGES + 8) * 4);               // +8 pad for unroll reads
    unsigned short* u  = (unsigned short*)alloc((size_t)(N_NODES + 1) * 128 * 2);  // +1 zero row
    unsigned short* u2 = (unsigned short*)alloc((size_t)(N_NODES + 1) * 128 * 2);  // +1 zero row

    hipMemsetAsync(bcount, 0, (size_t)NBUCK * 4, stream);
    k_prep_hist<<<384, 256, 0, stream>>>(W1, W2, wp1, wp2, dst, bcount,
                                         (unsigned int*)(u + (size_t)N_NODES * 128),
                                         (unsigned int*)(u2 + (size_t)N_NODES * 128), dinv);
    k_scan391<<<1, 512, 0, stream>>>(bcount, bbase, bcur, &offs[N_NODES]);
    k_bucket_g1<<<NBUCK + G1A, 256, 0, stream>>>(src, dst, bcur, pairs, x, wp1, u);
    k_bfill_g1<<<NBUCK + G1B, 256, 0, stream>>>(pairs, bbase, bcount, dinv, offs, csr, x, wp1, u);

    k_agg1_g2<<<N_NODES / 32, 512, 0, stream>>>((const unsigned int*)u, offs, csr, dinv, b1,
                                                wp2, u2);
    k_agg2<<<(N_NODES + 3) / 4, 256, 0, stream>>>((const unsigned int*)u2, offs, csr, dinv, b2,
                                                  Wl, pnode);

    k_fin<<<N_GRAPHS, 64, 0, stream>>>(pnode, batch, bl, out);
}

// Round 7
// 313.787 us; speedup vs baseline: 1.3765x; 1.0145x over previous
//
#include <hip/hip_runtime.h>
#include <hip/hip_bf16.h>

#define N_NODES 100000
#define N_EDGES 1600000
#define FEAT 128
#define N_GRAPHS 1024
#define NBUCK 391   // ceil(N_NODES/256) windows of 256 nodes (bucket = dst >> 8)
#define CHUNK 4096  // edges per k_bucket block
#define NTILES 1563 // ceil(N_NODES/64) gemm row tiles
#define G1A 781     // gemm1 tiles overlapped with bucket
#define G1B 782     // gemm1 tiles overlapped with bfill

typedef short short8 __attribute__((ext_vector_type(8)));
typedef float float4v __attribute__((ext_vector_type(4)));

static __device__ inline unsigned short f2bf(float f) {
    __hip_bfloat16 b = __float2bfloat16(f);
    unsigned short r;
    __builtin_memcpy(&r, &b, 2);
    return r;
}
static __device__ inline float bf_lo(unsigned int v) { return __uint_as_float(v << 16); }
static __device__ inline float bf_hi(unsigned int v) { return __uint_as_float(v & 0xFFFF0000u); }

// ---------------- dispatch 1: W-split prep (blocks 0..127) + dst histogram (blocks 128..383) ----------
__global__ __launch_bounds__(256) void k_prep_hist(const float* __restrict__ W1,
                                                   const float* __restrict__ W2,
                                                   unsigned short* __restrict__ wp1,
                                                   unsigned short* __restrict__ wp2,
                                                   const int* __restrict__ dst,
                                                   int* __restrict__ bcount,
                                                   unsigned int* __restrict__ udummy,
                                                   unsigned int* __restrict__ u2dummy,
                                                   float* __restrict__ dinv) {
    int bid = blockIdx.x;
    if (bid < 128) {
        const float* W = (bid < 64) ? W1 : W2;
        unsigned short* wp = (bid < 64) ? wp1 : wp2;
        int t = (bid & 63) * 256 + threadIdx.x;  // 0..16383
        int k = t >> 7, n = t & 127;
        float w = W[k * 128 + n];
        unsigned ub = __float_as_uint(w);
        unsigned short hi = (unsigned short)(ub >> 16);  // truncation split
        float hif = __uint_as_float(ub & 0xFFFF0000u);
        unsigned short lo = f2bf(w - hif);               // RNE residual
        int sidx = n * 128 + ((k & 7) | (8 * (((k >> 3) ^ n) & 15)));
        wp[sidx] = hi;
        wp[16384 + sidx] = lo;
        if (bid == 0) {
            if (threadIdx.x < 64) udummy[threadIdx.x] = 0;
            else if (threadIdx.x < 128) u2dummy[threadIdx.x - 64] = 0;
            else if (threadIdx.x == 128) dinv[N_NODES] = 0.f;
        }
    } else {
        __shared__ int h[NBUCK];
        for (int i = threadIdx.x; i < NBUCK; i += 256) h[i] = 0;
        __syncthreads();
        int hb = bid - 128;
        for (int e = hb * 256 + threadIdx.x; e < N_EDGES; e += 256 * 256)
            atomicAdd(&h[dst[e] >> 8], 1);
        __syncthreads();
        for (int i = threadIdx.x; i < NBUCK; i += 256) {
            int c = h[i];
            if (c) atomicAdd(&bcount[i], c);
        }
    }
}

// ---------------- dispatch 2: exclusive scan of 391 bucket counts (single block) ----------------
// bbase doubles as the CSR window base (wbase==bbase: per-bucket deg sum == bucket edge count).
__global__ __launch_bounds__(512) void k_scan391(const int* __restrict__ in,
                                                 int* __restrict__ base,
                                                 int* __restrict__ cur,
                                                 int* __restrict__ tail) {
    int t = threadIdx.x;
    int v = (t < NBUCK) ? in[t] : 0;
    int lane = t & 63, wid = t >> 6;
    int s = v;
#pragma unroll
    for (int d = 1; d < 64; d <<= 1) { int n = __shfl_up(s, d); if (lane >= d) s += n; }
    __shared__ int ws[8];
    if (lane == 63) ws[wid] = s;
    __syncthreads();
    if (t < 8) {
        int x = ws[t];
#pragma unroll
        for (int d = 1; d < 8; d <<= 1) { int n = __shfl_up(x, d); if ((int)t >= d) x += n; }
        ws[t] = x;
    }
    __syncthreads();
    int excl = s - v + (wid ? ws[wid - 1] : 0);
    if (t < NBUCK) {
        base[t] = excl;
        cur[t] = excl;
    }
    if (t == 0) tail[0] = N_EDGES;
}

// ---------------- shared gemm body: u = bf16(inp @ W) (UNSCALED — dinv applied in agg) ----------------
__device__ __forceinline__ void gemm_f32_body(int tile, const float* __restrict__ inp,
                                              const unsigned short* __restrict__ wp,
                                              unsigned short* __restrict__ u) {
    __shared__ unsigned short sW[32768];  // 64 KB: hi | lo (swizzled)
    {
        float4* d4 = (float4*)sW;
        const float4* s4 = (const float4*)wp;
#pragma unroll
        for (int i = 0; i < 16; ++i) d4[threadIdx.x + 256 * i] = s4[threadIdx.x + 256 * i];
    }
    __syncthreads();
    const int t = threadIdx.x;
    const int wv = t >> 6, L = t & 63;
    const int m = L & 15, q = L >> 4;
    const int r0 = tile * 64 + wv * 16;
    int arow = r0 + m;
    if (arow >= N_NODES) arow = N_NODES - 1;
    const float4* ap = (const float4*)(inp + (size_t)arow * 128);
    float4v acc[8];
#pragma unroll
    for (int c = 0; c < 8; ++c) acc[c] = (float4v){0.f, 0.f, 0.f, 0.f};
#pragma unroll
    for (int k0 = 0; k0 < 128; k0 += 32) {
        float4 f0 = ap[(k0 >> 2) + 2 * q];
        float4 f1 = ap[(k0 >> 2) + 2 * q + 1];
        float fa[8] = {f0.x, f0.y, f0.z, f0.w, f1.x, f1.y, f1.z, f1.w};
        short8 ah, al;
#pragma unroll
        for (int j = 0; j < 8; ++j) {
            unsigned ub = __float_as_uint(fa[j]);
            ah[j] = (short)(ub >> 16);
            float hif = __uint_as_float(ub & 0xFFFF0000u);
            al[j] = (short)f2bf(fa[j] - hif);
        }
        const int b = (k0 >> 3) + q;
#pragma unroll
        for (int c = 0; c < 8; ++c) {
            int ng = c * 16 + m;
            int elem = ng * 128 + 8 * ((b ^ ng) & 15);
            short8 bh = *(const short8*)&sW[elem];
            short8 bl = *(const short8*)&sW[16384 + elem];
            acc[c] = __builtin_amdgcn_mfma_f32_16x16x32_bf16(ah, bh, acc[c], 0, 0, 0);
            acc[c] = __builtin_amdgcn_mfma_f32_16x16x32_bf16(al, bh, acc[c], 0, 0, 0);
            acc[c] = __builtin_amdgcn_mfma_f32_16x16x32_bf16(ah, bl, acc[c], 0, 0, 0);
        }
    }
#pragma unroll
    for (int r = 0; r < 4; ++r) {
        int row = r0 + 4 * q + r;
        if (row < N_NODES) {
            unsigned short* up = u + (size_t)row * 128 + m;
#pragma unroll
            for (int c = 0; c < 8; ++c) up[c * 16] = f2bf(acc[c][r]);
        }
    }
}

// ---------------- dispatch 3: bucket binning (blocks 0..390) + gemm1 tiles 0..780 ----------------
__global__ __launch_bounds__(256) void k_bucket_g1(const int* __restrict__ src,
                                                   const int* __restrict__ dst,
                                                   int* __restrict__ bcur,
                                                   unsigned int* __restrict__ pairs,
                                                   const float* __restrict__ x,
                                                   const unsigned short* __restrict__ wp1,
                                                   unsigned short* __restrict__ u) {
    if (blockIdx.x >= NBUCK) {
        gemm_f32_body(blockIdx.x - NBUCK, x, wp1, u);
        return;
    }
    __shared__ int cnt[NBUCK];
    __shared__ int basebuf[NBUCK];
    int t = threadIdx.x;
    int e0 = blockIdx.x * CHUNK;
    for (int i = t; i < NBUCK; i += 256) cnt[i] = 0;
    __syncthreads();
    unsigned pk[16]; int bk[16];
#pragma unroll
    for (int j = 0; j < 16; ++j) {
        int e = e0 + j * 256 + t;
        if (e < N_EDGES) {
            int s = src[e], d = dst[e];
            bk[j] = d >> 8;
            pk[j] = ((unsigned)s << 8) | (unsigned)(d & 255);
            atomicAdd(&cnt[bk[j]], 1);
        } else bk[j] = -1;
    }
    __syncthreads();
    for (int i = t; i < NBUCK; i += 256) {
        int c = cnt[i];
        basebuf[i] = c ? atomicAdd(&bcur[i], c) : 0;
        cnt[i] = 0;
    }
    __syncthreads();
#pragma unroll
    for (int j = 0; j < 16; ++j) {
        if (bk[j] >= 0) {
            int p = basebuf[bk[j]] + atomicAdd(&cnt[bk[j]], 1);
            pairs[p] = pk[j];
        }
    }
}

// ---------------- dispatch 4: fused deg+dinv+offs+csr fill (blocks 0..390) + gemm1 tiles 781..1562 ----
__global__ __launch_bounds__(256) void k_bfill_g1(const unsigned int* __restrict__ pairs,
                                                  const int* __restrict__ bbase,
                                                  const int* __restrict__ bcount,
                                                  float* __restrict__ dinv,
                                                  int* __restrict__ offs,
                                                  int* __restrict__ csr,
                                                  const float* __restrict__ x,
                                                  const unsigned short* __restrict__ wp1,
                                                  unsigned short* __restrict__ u) {
    if (blockIdx.x >= NBUCK) {
        gemm_f32_body(blockIdx.x - NBUCK + G1A, x, wp1, u);
        return;
    }
    __shared__ int degl[256];
    __shared__ int lcur[256];
    __shared__ int ws[4];
    int b = blockIdx.x, t = threadIdx.x;
    degl[t] = 0;
    __syncthreads();
    int s0 = bbase[b], n = bcount[b];
    for (int i = t; i < n; i += 256) atomicAdd(&degl[pairs[s0 + i] & 255u], 1);
    __syncthreads();
    int node = b * 256 + t;
    int dv = degl[t];
    if (node < N_NODES) dinv[node] = rsqrtf((float)(dv + 1));  // +1 self-loop
    int lane = t & 63, wid = t >> 6;
    int s = dv;
#pragma unroll
    for (int d = 1; d < 64; d <<= 1) { int nn = __shfl_up(s, d); if (lane >= d) s += nn; }
    if (lane == 63) ws[wid] = s;
    __syncthreads();
    if (t < 4) {
        int xx = ws[t];
#pragma unroll
        for (int d = 1; d < 4; d <<= 1) { int nn = __shfl_up(xx, d); if ((int)t >= d) xx += nn; }
        ws[t] = xx;
    }
    __syncthreads();
    int excl = s - dv + (wid ? ws[wid - 1] : 0) + bbase[b];  // wbase == bbase
    if (node < N_NODES) offs[node] = excl;
    lcur[t] = excl;
    __syncthreads();
    for (int i = t; i < n; i += 256) {
        unsigned pr = pairs[s0 + i];
        int p = atomicAdd(&lcur[pr & 255u], 1);
        csr[p] = (int)(pr >> 8);
    }
}

// ---------------- fused agg1 + gemm2: u2 = bf16(relu(Ahat@u + b1) @ W2) ----------------
// 512 threads, 32 nodes/block (100000 = 3125*32 exact). LDS 16 KB (h rows only).
// R6 counters: VGPR=28 proved the compiler issued phase-2 W2 global loads JIT -> 4 serial
// 200-500cyc chains per wave. R7: software-pipeline them — prologue quad issued BEFORE the
// barrier (completes during the barrier's vmcnt drain, free), and k0+1's quad prefetched
// before k0's MFMAs. +32 VGPR held; must stay <=64 for 32 waves/CU (tripwire: VGPR_Count>64).
__global__ __launch_bounds__(512, 6) void k_agg1_g2(const unsigned int* __restrict__ u,
                                                    const int* __restrict__ offs,
                                                    const int* __restrict__ csr,
                                                    const float* __restrict__ dinv,
                                                    const float* __restrict__ bias,
                                                    const unsigned short* __restrict__ wp,
                                                    unsigned short* __restrict__ u2) {
    __shared__ float hS[32 * 128];         // 16 KB h rows (float4-group XOR swizzle)
    const int w = threadIdx.x >> 6;
    const int lane = threadIdx.x & 63;
    const int base = blockIdx.x * 32;

    // ---- phase 1: aggregation (4 nodes per wave, sequential) ----
    for (int n = 0; n < 4; ++n) {
        const int row = 4 * w + n;
        const int node = base + row;  // always < N_NODES
        int p = __builtin_amdgcn_readfirstlane(offs[node]);
        int e = __builtin_amdgcn_readfirstlane(offs[node + 1]);
        float dsf = dinv[node];
        unsigned int self = u[(size_t)node * 64 + lane];
        float ax0 = dsf * bf_lo(self), ay0 = dsf * bf_hi(self);
        float ax1 = 0.f, ay1 = 0.f, ax2 = 0.f, ay2 = 0.f, ax3 = 0.f, ay3 = 0.f;
        float ax4 = 0.f, ay4 = 0.f, ax5 = 0.f, ay5 = 0.f, ax6 = 0.f, ay6 = 0.f;
        float ax7 = 0.f, ay7 = 0.f;
        for (; p < e; p += 8) {
            int c0 = csr[p + 0], c1 = csr[p + 1], c2 = csr[p + 2], c3 = csr[p + 3];
            int c4 = csr[p + 4], c5 = csr[p + 5], c6 = csr[p + 6], c7 = csr[p + 7];
            int i0 = c0;
            int i1 = (p + 1 < e) ? c1 : N_NODES;
            int i2 = (p + 2 < e) ? c2 : N_NODES;
            int i3 = (p + 3 < e) ? c3 : N_NODES;
            int i4 = (p + 4 < e) ? c4 : N_NODES;
            int i5 = (p + 5 < e) ? c5 : N_NODES;
            int i6 = (p + 6 < e) ? c6 : N_NODES;
            int i7 = (p + 7 < e) ? c7 : N_NODES;
            float d0 = dinv[i0], d1 = dinv[i1], d2 = dinv[i2], d3 = dinv[i3];
            float d4 = dinv[i4], d5 = dinv[i5], d6 = dinv[i6], d7 = dinv[i7];
            unsigned v0 = (u + (size_t)i0 * 64)[lane];
            unsigned v1 = (u + (size_t)i1 * 64)[lane];
            unsigned v2 = (u + (size_t)i2 * 64)[lane];
            unsigned v3 = (u + (size_t)i3 * 64)[lane];
            unsigned v4 = (u + (size_t)i4 * 64)[lane];
            unsigned v5 = (u + (size_t)i5 * 64)[lane];
            unsigned v6 = (u + (size_t)i6 * 64)[lane];
            unsigned v7 = (u + (size_t)i7 * 64)[lane];
            ax0 = fmaf(d0, bf_lo(v0), ax0); ay0 = fmaf(d0, bf_hi(v0), ay0);
            ax1 = fmaf(d1, bf_lo(v1), ax1); ay1 = fmaf(d1, bf_hi(v1), ay1);
            ax2 = fmaf(d2, bf_lo(v2), ax2); ay2 = fmaf(d2, bf_hi(v2), ay2);
            ax3 = fmaf(d3, bf_lo(v3), ax3); ay3 = fmaf(d3, bf_hi(v3), ay3);
            ax4 = fmaf(d4, bf_lo(v4), ax4); ay4 = fmaf(d4, bf_hi(v4), ay4);
            ax5 = fmaf(d5, bf_lo(v5), ax5); ay5 = fmaf(d5, bf_hi(v5), ay5);
            ax6 = fmaf(d6, bf_lo(v6), ax6); ay6 = fmaf(d6, bf_hi(v6), ay6);
            ax7 = fmaf(d7, bf_lo(v7), ax7); ay7 = fmaf(d7, bf_hi(v7), ay7);
        }
        float2 b = ((const float2*)bias)[lane];
        float sx = ((ax0 + ax1) + (ax2 + ax3)) + ((ax4 + ax5) + (ax6 + ax7));
        float sy = ((ay0 + ay1) + (ay2 + ay3)) + ((ay4 + ay5) + (ay6 + ay7));
        float r0 = fmaxf(dsf * sx + b.x, 0.f);
        float r1 = fmaxf(dsf * sy + b.y, 0.f);
        // swizzled LDS write: k = 2*lane -> float4-group g = lane>>1, phys group = g ^ (row&7)
        int g4 = (lane >> 1) ^ (row & 7);
        float2* hp = (float2*)&hS[row * 128 + g4 * 4 + (lane & 1) * 2];
        *hp = (float2){r0, r1};
    }

    // ---- phase 2 setup + prologue W2 prefetch (issued BEFORE the barrier: no phase-1 dep;
    //      the barrier's vmcnt drain completes them for free) ----
    const int m = lane & 15, q = lane >> 4;
    const int rt = w >> 2;   // row-tile 0/1 (rows 16*rt..16*rt+15)
    const int cw = w & 3;    // column quarter (cols 32*cw..32*cw+31)
    const int arow = 16 * rt + m;
    const int ng0 = (2 * cw + 0) * 16 + m;
    const int ng1 = (2 * cw + 1) * 16 + m;
    short8 bh0, bl0, bh1, bl1;
    {
        int b = q;  // ks=0: b = 4*0 + q
        int e0 = ng0 * 128 + 8 * ((b ^ ng0) & 15);
        int e1 = ng1 * 128 + 8 * ((b ^ ng1) & 15);
        bh0 = *(const short8*)&wp[e0];
        bl0 = *(const short8*)&wp[16384 + e0];
        bh1 = *(const short8*)&wp[e1];
        bl1 = *(const short8*)&wp[16384 + e1];
    }
    __syncthreads();

    // ---- phase 2: u2[base..base+31] = bf16(h @ W2), 3-MFMA hi/lo, k0-pipelined W2 loads ----
    float4v acc0 = (float4v){0.f, 0.f, 0.f, 0.f};
    float4v acc1 = (float4v){0.f, 0.f, 0.f, 0.f};
#pragma unroll
    for (int ks = 0; ks < 4; ++ks) {
        short8 nh0, nl0, nh1, nl1;
        if (ks < 3) {
            int b = 4 * (ks + 1) + q;
            int e0 = ng0 * 128 + 8 * ((b ^ ng0) & 15);
            int e1 = ng1 * 128 + 8 * ((b ^ ng1) & 15);
            nh0 = *(const short8*)&wp[e0];
            nl0 = *(const short8*)&wp[16384 + e0];
            nh1 = *(const short8*)&wp[e1];
            nl1 = *(const short8*)&wp[16384 + e1];
        }
        const int k0 = 32 * ks;
        int g1 = (k0 >> 2) + 2 * q;
        float4 f0 = *(const float4*)&hS[arow * 128 + ((g1 ^ (arow & 7)) << 2)];
        float4 f1 = *(const float4*)&hS[arow * 128 + (((g1 + 1) ^ (arow & 7)) << 2)];
        float fa[8] = {f0.x, f0.y, f0.z, f0.w, f1.x, f1.y, f1.z, f1.w};
        short8 ah, al;
#pragma unroll
        for (int j = 0; j < 8; ++j) {
            unsigned ub = __float_as_uint(fa[j]);
            ah[j] = (short)(ub >> 16);
            float hif = __uint_as_float(ub & 0xFFFF0000u);
            al[j] = (short)f2bf(fa[j] - hif);
        }
        acc0 = __builtin_amdgcn_mfma_f32_16x16x32_bf16(ah, bh0, acc0, 0, 0, 0);
        acc0 = __builtin_amdgcn_mfma_f32_16x16x32_bf16(al, bh0, acc0, 0, 0, 0);
        acc0 = __builtin_amdgcn_mfma_f32_16x16x32_bf16(ah, bl0, acc0, 0, 0, 0);
        acc1 = __builtin_amdgcn_mfma_f32_16x16x32_bf16(ah, bh1, acc1, 0, 0, 0);
        acc1 = __builtin_amdgcn_mfma_f32_16x16x32_bf16(al, bh1, acc1, 0, 0, 0);
        acc1 = __builtin_amdgcn_mfma_f32_16x16x32_bf16(ah, bl1, acc1, 0, 0, 0);
        if (ks < 3) {
            bh0 = nh0; bl0 = nl0; bh1 = nh1; bl1 = nl1;
        }
    }
#pragma unroll
    for (int r = 0; r < 4; ++r) {
        int row = 16 * rt + 4 * q + r;
        unsigned short* up = u2 + (size_t)(base + row) * 128 + m;
        up[(2 * cw + 0) * 16] = f2bf(acc0[r]);
        up[(2 * cw + 1) * 16] = f2bf(acc1[r]);
    }
}

// ---------------- agg2 (layer 2, pool-fused): project h2 onto Wl, per-node partial to pnode ----
__global__ __launch_bounds__(256) void k_agg2(const unsigned int* __restrict__ u,
                                              const int* __restrict__ offs,
                                              const int* __restrict__ csr,
                                              const float* __restrict__ dinv,
                                              const float* __restrict__ bias,
                                              const float* __restrict__ Wl,
                                              float* __restrict__ pnode) {
    int wid = threadIdx.x >> 6;
    int lane = threadIdx.x & 63;
    int node = __builtin_amdgcn_readfirstlane(blockIdx.x * 4 + wid);
    if (node >= N_NODES) return;
    int p = __builtin_amdgcn_readfirstlane(offs[node]);
    int e = __builtin_amdgcn_readfirstlane(offs[node + 1]);
    float dsf = dinv[node];
    unsigned int self = u[(size_t)node * 64 + lane];
    float ax0 = dsf * bf_lo(self), ay0 = dsf * bf_hi(self);
    float ax1 = 0.f, ay1 = 0.f, ax2 = 0.f, ay2 = 0.f, ax3 = 0.f, ay3 = 0.f;
    float ax4 = 0.f, ay4 = 0.f, ax5 = 0.f, ay5 = 0.f, ax6 = 0.f, ay6 = 0.f;
    float ax7 = 0.f, ay7 = 0.f;
    for (; p < e; p += 8) {
        int c0 = csr[p + 0], c1 = csr[p + 1], c2 = csr[p + 2], c3 = csr[p + 3];
        int c4 = csr[p + 4], c5 = csr[p + 5], c6 = csr[p + 6], c7 = csr[p + 7];
        int i0 = c0;
        int i1 = (p + 1 < e) ? c1 : N_NODES;
        int i2 = (p + 2 < e) ? c2 : N_NODES;
        int i3 = (p + 3 < e) ? c3 : N_NODES;
        int i4 = (p + 4 < e) ? c4 : N_NODES;
        int i5 = (p + 5 < e) ? c5 : N_NODES;
        int i6 = (p + 6 < e) ? c6 : N_NODES;
        int i7 = (p + 7 < e) ? c7 : N_NODES;
        float d0 = dinv[i0], d1 = dinv[i1], d2 = dinv[i2], d3 = dinv[i3];
        float d4 = dinv[i4], d5 = dinv[i5], d6 = dinv[i6], d7 = dinv[i7];
        unsigned v0 = (u + (size_t)i0 * 64)[lane];
        unsigned v1 = (u + (size_t)i1 * 64)[lane];
        unsigned v2 = (u + (size_t)i2 * 64)[lane];
        unsigned v3 = (u + (size_t)i3 * 64)[lane];
        unsigned v4 = (u + (size_t)i4 * 64)[lane];
        unsigned v5 = (u + (size_t)i5 * 64)[lane];
        unsigned v6 = (u + (size_t)i6 * 64)[lane];
        unsigned v7 = (u + (size_t)i7 * 64)[lane];
        ax0 = fmaf(d0, bf_lo(v0), ax0); ay0 = fmaf(d0, bf_hi(v0), ay0);
        ax1 = fmaf(d1, bf_lo(v1), ax1); ay1 = fmaf(d1, bf_hi(v1), ay1);
        ax2 = fmaf(d2, bf_lo(v2), ax2); ay2 = fmaf(d2, bf_hi(v2), ay2);
        ax3 = fmaf(d3, bf_lo(v3), ax3); ay3 = fmaf(d3, bf_hi(v3), ay3);
        ax4 = fmaf(d4, bf_lo(v4), ax4); ay4 = fmaf(d4, bf_hi(v4), ay4);
        ax5 = fmaf(d5, bf_lo(v5), ax5); ay5 = fmaf(d5, bf_hi(v5), ay5);
        ax6 = fmaf(d6, bf_lo(v6), ax6); ay6 = fmaf(d6, bf_hi(v6), ay6);
        ax7 = fmaf(d7, bf_lo(v7), ax7); ay7 = fmaf(d7, bf_hi(v7), ay7);
    }
    float2 b = ((const float2*)bias)[lane];
    float sx = ((ax0 + ax1) + (ax2 + ax3)) + ((ax4 + ax5) + (ax6 + ax7));
    float sy = ((ay0 + ay1) + (ay2 + ay3)) + ((ay4 + ay5) + (ay6 + ay7));
    float r0 = fmaxf(dsf * sx + b.x, 0.f);
    float r1 = fmaxf(dsf * sy + b.y, 0.f);
    // fused pool projection: lane holds channels (2*lane, 2*lane+1); Wl row-major [128][2].
    float2 wl0 = ((const float2*)Wl)[2 * lane];
    float2 wl1 = ((const float2*)Wl)[2 * lane + 1];
    float p0 = r0 * wl0.x + r1 * wl1.x;
    float p1 = r0 * wl0.y + r1 * wl1.y;
#pragma unroll
    for (int d = 32; d > 0; d >>= 1) {
        p0 += __shfl_xor(p0, d);
        p1 += __shfl_xor(p1, d);
    }
    if (lane == 0) {
        float2* pp = (float2*)pnode;
        pp[node] = (float2){p0, p1};
    }
}

// ---------------- finalize: out[g] = segsum(pnode)/max(cnt,1) + bl (1 wave per graph) ----------
__global__ __launch_bounds__(64) void k_fin(const float* __restrict__ pnode,
                                            const int* __restrict__ batch,
                                            const float* __restrict__ bl,
                                            float* __restrict__ out) {
    int g = blockIdx.x;
    int lane = threadIdx.x;
    __shared__ int sb[2];
    if (lane < 2) {
        int tgt = g + lane;
        int lo = 0, hi = N_NODES;
        while (lo < hi) { int m = (lo + hi) >> 1; if (batch[m] < tgt) lo = m + 1; else hi = m; }
        sb[lane] = lo;
    }
    __syncthreads();
    int s0 = sb[0], s1 = sb[1];
    const float2* pp = (const float2*)pnode;
    float p0 = 0.f, p1 = 0.f;
    for (int i = s0 + lane; i < s1; i += 64) {
        float2 v = pp[i];
        p0 += v.x;
        p1 += v.y;
    }
#pragma unroll
    for (int d = 32; d > 0; d >>= 1) {
        p0 += __shfl_xor(p0, d);
        p1 += __shfl_xor(p1, d);
    }
    if (lane == 0) {
        float inv = 1.f / fmaxf((float)(s1 - s0), 1.f);
        out[2 * g + 0] = p0 * inv + bl[0];
        out[2 * g + 1] = p1 * inv + bl[1];
    }
}

extern "C" void kernel_launch(void* const* d_in, const int* in_sizes, int n_in,
                              void* d_out, int out_size, void* d_ws, size_t ws_size,
                              hipStream_t stream) {
    const float* x  = (const float*)d_in[0];
    const int* ei   = (const int*)d_in[1];
    const int* batch = (const int*)d_in[2];
    const float* W1 = (const float*)d_in[3];
    const float* b1 = (const float*)d_in[4];
    const float* W2 = (const float*)d_in[5];
    const float* b2 = (const float*)d_in[6];
    const float* Wl = (const float*)d_in[7];
    const float* bl = (const float*)d_in[8];
    float* out = (float*)d_out;
    const int* src = ei;
    const int* dst = ei + N_EDGES;

    char* ws = (char*)d_ws;
    size_t o = 0;
    auto alloc = [&](size_t bytes) -> void* {
        o = (o + 255) & ~(size_t)255;
        void* p = ws + o;
        o += bytes;
        return p;
    };
    int* bcount = (int*)alloc((size_t)NBUCK * 4);
    int* bbase  = (int*)alloc((size_t)NBUCK * 4);
    int* bcur   = (int*)alloc((size_t)NBUCK * 4);
    float* dinv = (float*)alloc((size_t)(N_NODES + 1) * 4);  // +1 zero slot for tail
    int* offs   = (int*)alloc((size_t)(N_NODES + 1) * 4);
    unsigned short* wp1 = (unsigned short*)alloc(65536);
    unsigned short* wp2 = (unsigned short*)alloc(65536);
    float* pnode = (float*)alloc((size_t)N_NODES * 2 * 4);
    unsigned int* pairs = (unsigned int*)alloc((size_t)N_EDGES * 4);
    int* csr    = (int*)alloc((size_t)(N_EDGES + 8) * 4);               // +8 pad for unroll reads
    unsigned short* u  = (unsigned short*)alloc((size_t)(N_NODES + 1) * 128 * 2);  // +1 zero row
    unsigned short* u2 = (unsigned short*)alloc((size_t)(N_NODES + 1) * 128 * 2);  // +1 zero row

    hipMemsetAsync(bcount, 0, (size_t)NBUCK * 4, stream);
    k_prep_hist<<<384, 256, 0, stream>>>(W1, W2, wp1, wp2, dst, bcount,
                                         (unsigned int*)(u + (size_t)N_NODES * 128),
                                         (unsigned int*)(u2 + (size_t)N_NODES * 128), dinv);
    k_scan391<<<1, 512, 0, stream>>>(bcount, bbase, bcur, &offs[N_NODES]);
    k_bucket_g1<<<NBUCK + G1A, 256, 0, stream>>>(src, dst, bcur, pairs, x, wp1, u);
    k_bfill_g1<<<NBUCK + G1B, 256, 0, stream>>>(pairs, bbase, bcount, dinv, offs, csr, x, wp1, u);

    k_agg1_g2<<<N_NODES / 32, 512, 0, stream>>>((const unsigned int*)u, offs, csr, dinv, b1,
                                                wp2, u2);
    k_agg2<<<(N_NODES + 3) / 4, 256, 0, stream>>>((const unsigned int*)u2, offs, csr, dinv, b2,
                                                  Wl, pnode);

    k_fin<<<N_GRAPHS, 64, 0, stream>>>(pnode, batch, bl, out);
}